// Round 9
// baseline (266.749 us; speedup 1.0000x reference)
//
#include <hip/hip_runtime.h>
#include <stdint.h>

#define KNB   16
#define GD    64                    // grid cells per axis
#define GTOT  (GD * GD * GD)        // 262144 cells
#define GORIG (-6.5f)
#define GEDGE 0.203125f             // 13.0 / 64
#define GINV  (1.0f / GEDGE)
#define CAPW  640                   // per-query candidate capacity (10 x 64)

typedef short short8 __attribute__((ext_vector_type(8)));
typedef float floatx4 __attribute__((ext_vector_type(4)));

__device__ __forceinline__ unsigned short f2bf(float x) {
  union { float f; uint32_t u; } v; v.f = x;
  uint32_t u = v.u + 0x7FFFu + ((v.u >> 16) & 1u);   // RNE
  return (unsigned short)(u >> 16);
}
__device__ __forceinline__ float bf2f(unsigned short b) {
  return __uint_as_float(((uint32_t)b) << 16);
}
__device__ __forceinline__ int cellco(float v) {
  int c = (int)floorf((v - GORIG) * GINV);
  return c < 0 ? 0 : (c > GD - 1 ? GD - 1 : c);
}

// ---------------------------------------------------------------------------
// zero: count[GTOT] = 0  (must run before prep's atomics, every launch)
// ---------------------------------------------------------------------------
__global__ void zero_kernel(int* __restrict__ count) {
  int i = (blockIdx.x * 256 + threadIdx.x) * 4;
  *(int4*)(count + i) = make_int4(0, 0, 0, 0);
}

// ---------------------------------------------------------------------------
// prep: xb = bf16(x); pos4 = {x,y,z,pp}; ptcell[j] + count atomics; Wt.
// ---------------------------------------------------------------------------
__global__ void prep_kernel(const float* __restrict__ x,
                            const float* __restrict__ pos,
                            const float* __restrict__ W_att,
                            unsigned short* __restrict__ xb,
                            float4* __restrict__ pos4,
                            unsigned short* __restrict__ Wt,
                            int* __restrict__ ptcell,
                            int* __restrict__ count, int N) {
  int id = blockIdx.x * 256 + threadIdx.x;
  int nx8 = N * 8;
  if (id < nx8) {
    const float4* src = (const float4*)x + (size_t)id * 2;
    float4 a = src[0], b = src[1];
    short8 v;
    v[0] = (short)f2bf(a.x); v[1] = (short)f2bf(a.y);
    v[2] = (short)f2bf(a.z); v[3] = (short)f2bf(a.w);
    v[4] = (short)f2bf(b.x); v[5] = (short)f2bf(b.y);
    v[6] = (short)f2bf(b.z); v[7] = (short)f2bf(b.w);
    *(short8*)(xb + (size_t)id * 8) = v;
  } else if (id < nx8 + N) {
    int j = id - nx8;
    float px = pos[3 * j], py = pos[3 * j + 1], pz = pos[3 * j + 2];
    float pp = fmaf(px, px, fmaf(py, py, pz * pz));
    pos4[j] = make_float4(px, py, pz, pp);
    int cid = (cellco(pz) * GD + cellco(py)) * GD + cellco(px);
    ptcell[j] = cid;
    atomicAdd(&count[cid], 1);
  } else if (id < nx8 + N + 128 * 128) {
    int t = id - nx8 - N;
    int c = t >> 7, f = t & 127;
    Wt[f * 128 + c] = f2bf(W_att[t]);
  }
}

// ---------------------------------------------------------------------------
// two-level exclusive scan of count[GTOT] -> cell_start / cursor
// ---------------------------------------------------------------------------
__global__ __launch_bounds__(256) void scan1(const int* __restrict__ count,
                                             int* __restrict__ partial) {
  int b = blockIdx.x, t = threadIdx.x;
  int v = count[b * 256 + t];
#pragma unroll
  for (int off = 1; off < 64; off <<= 1) v += __shfl_xor(v, off);
  __shared__ int ws_[4];
  if ((t & 63) == 0) ws_[t >> 6] = v;
  __syncthreads();
  if (t == 0) partial[b] = ws_[0] + ws_[1] + ws_[2] + ws_[3];
}

__global__ __launch_bounds__(256) void scan2(int* __restrict__ partial,
                                             int* __restrict__ cell_start) {
  int t = threadIdx.x;
  int v0 = partial[t * 4], v1 = partial[t * 4 + 1];
  int v2 = partial[t * 4 + 2], v3 = partial[t * 4 + 3];
  int s1 = v0 + v1, s2 = s1 + v2, s3 = s2 + v3;
  int x = s3;
  int lane = t & 63, wv = t >> 6;
#pragma unroll
  for (int off = 1; off < 64; off <<= 1) {
    int y = __shfl_up(x, off);
    if (lane >= off) x += y;
  }
  __shared__ int wsum[4];
  if (lane == 63) wsum[wv] = x;
  __syncthreads();
  int base = 0;
  for (int k = 0; k < wv; ++k) base += wsum[k];
  int excl = base + x - s3;
  partial[t * 4]     = excl;
  partial[t * 4 + 1] = excl + v0;
  partial[t * 4 + 2] = excl + s1;
  partial[t * 4 + 3] = excl + s2;
  if (t == 255) cell_start[GTOT] = excl + s3;   // = N
}

__global__ __launch_bounds__(256) void scan3(const int* __restrict__ count,
                                             const int* __restrict__ partial,
                                             int* __restrict__ cell_start,
                                             int* __restrict__ cursor) {
  int b = blockIdx.x, t = threadIdx.x;
  int v = count[b * 256 + t];
  int x = v;
  int lane = t & 63, wv = t >> 6;
#pragma unroll
  for (int off = 1; off < 64; off <<= 1) {
    int y = __shfl_up(x, off);
    if (lane >= off) x += y;
  }
  __shared__ int wsum[4];
  if (lane == 63) wsum[wv] = x;
  __syncthreads();
  int base = partial[b];
  for (int k = 0; k < wv; ++k) base += wsum[k];
  int excl = base + x - v;
  cell_start[b * 256 + t] = excl;
  cursor[b * 256 + t] = excl;
}

// ---------------------------------------------------------------------------
// scatter: points into cell-sorted order (spos4 + original index sid)
// ---------------------------------------------------------------------------
__global__ void scatter_kernel(const float4* __restrict__ pos4,
                               const int* __restrict__ ptcell,
                               int* __restrict__ cursor,
                               float4* __restrict__ spos4,
                               int* __restrict__ sid, int N) {
  int j = blockIdx.x * 256 + threadIdx.x;
  if (j >= N) return;
  int cid = ptcell[j];
  int slot = atomicAdd(&cursor[cid], 1);
  spos4[slot] = pos4[j];
  sid[slot] = j;
}

// ---------------------------------------------------------------------------
// knn_grid (R9): one wave per query. GEOMETRIC shell doubling s in
// {1,2,4,8,16,32,63}: each stage drains the annulus between cube(s_lo) and
// cube(s). Rows with max(|dz|,|dy|) > s_lo are full contiguous x-rows
// [cqx-s, cqx+s]; inner rows contribute two x-segments [cqx-s, cqx-s_lo-1]
// and [cqx+s_lo+1, cqx+s] (the already-drained inner cube excluded exactly).
// (dz,dy) enumeration clamped to grid bounds. Cuts worst-case cumulative
// enumeration from O(S^3) (~8300 wave-batches at S=40) to ~100 batches.
// Flat cooperative drain, compaction-to-top-16 overflow proofing, taukey
// filter, termination (>=16 stored within r_expl; clamped sides = inf) and
// extraction are all byte-identical to the R8-proven machinery.
// ---------------------------------------------------------------------------
__global__ __launch_bounds__(256) void knn_grid(
    const float4* __restrict__ pos4, const float4* __restrict__ spos4,
    const int* __restrict__ sid, const int* __restrict__ cell_start,
    const int* __restrict__ idx, int* __restrict__ nbr, int M) {
  __shared__ unsigned long long cand[4][CAPW];
  __shared__ uint32_t rsA[4][64], rlA[4][64], rsB[4][64];
  __shared__ uint32_t rps[4][72];   // ps[0..64], padded
  const int tid = threadIdx.x, wv = tid >> 6, ln = tid & 63;
  const int m = blockIdx.x * 4 + wv;
  if (m >= M) return;

  const float4 qp = pos4[idx[m]];
  const int cqx = cellco(qp.x), cqy = cellco(qp.y), cqz = cellco(qp.z);

  int tot = 0;
  unsigned long long taukey = ~0ull;   // store filter (max until first compact)
  int s_lo = -1;                       // first stage: whole cube (incl center)
  bool done = false;
  for (int si = 0; si < 7 && !done; ++si) {
    const int s = (si == 6) ? 63 : (1 << si);
    const int z0 = (cqz - s < 0) ? 0 : cqz - s;
    const int z1 = (cqz + s > GD - 1) ? GD - 1 : cqz + s;
    const int y0 = (cqy - s < 0) ? 0 : cqy - s;
    const int y1 = (cqy + s > GD - 1) ? GD - 1 : cqy + s;
    const int wy = y1 - y0 + 1;
    const int npair = (z1 - z0 + 1) * wy;
    for (int base = 0; base < npair; base += 64) {
      int i = base + ln;
      int stA = 0, lA = 0, stB = 0, lB = 0;
      if (i < npair) {
        int zz = z0 + i / wy;
        int yy = y0 + (i - (i / wy) * wy);
        int dz = zz - cqz, dy = yy - cqy;
        int az = dz < 0 ? -dz : dz, ay = dy < 0 ? -dy : dy;
        int ch = az > ay ? az : ay;
        int rowbase = (zz * GD + yy) * GD;
        if (ch > s_lo) {
          // full contiguous x-row [cqx-s, cqx+s] clipped
          int x0 = cqx - s; if (x0 < 0) x0 = 0;
          int x1 = cqx + s; if (x1 > GD - 1) x1 = GD - 1;
          stA = cell_start[rowbase + x0];
          lA  = cell_start[rowbase + x1 + 1] - stA;
        } else {
          // inner row: annulus segments left/right of drained cube
          int xl0 = cqx - s; if (xl0 < 0) xl0 = 0;
          int xl1 = cqx - s_lo - 1;
          if (xl1 >= xl0) {
            stA = cell_start[rowbase + xl0];
            lA  = cell_start[rowbase + xl1 + 1] - stA;
          }
          int xr0 = cqx + s_lo + 1;
          int xr1 = cqx + s; if (xr1 > GD - 1) xr1 = GD - 1;
          if (xr1 >= xr0) {
            stB = cell_start[rowbase + xr0];
            lB  = cell_start[rowbase + xr1 + 1] - stB;
          }
        }
      }
      // wave prefix sum of per-lane lengths -> flat layout
      int len = lA + lB;
      int xinc = len;
#pragma unroll
      for (int off = 1; off < 64; off <<= 1) {
        int y = __shfl_up(xinc, off);
        if (ln >= off) xinc += y;
      }
      int T = __shfl(xinc, 63);
      if (T == 0) continue;
      rps[wv][ln] = (uint32_t)(xinc - len);   // exclusive prefix
      rsA[wv][ln] = (uint32_t)stA;
      rlA[wv][ln] = (uint32_t)lA;
      rsB[wv][ln] = (uint32_t)stB;

      for (int b2 = 0; b2 < T; b2 += 64) {
        // --- overflow-proof: compact to exact top-16 before store ---
        if (tot + 64 > CAPW) {
          unsigned long long c[CAPW / 64];
#pragma unroll
          for (int chk = 0; chk < CAPW / 64; ++chk) {
            int slot = chk * 64 + ln;
            c[chk] = (slot < tot) ? cand[wv][slot] : ~0ull;
          }
          unsigned long long last = 0;
#pragma unroll
          for (int r = 0; r < KNB; ++r) {
            unsigned long long mn = c[0];
#pragma unroll
            for (int chk = 1; chk < CAPW / 64; ++chk)
              mn = (c[chk] < mn) ? c[chk] : mn;
#pragma unroll
            for (int off = 1; off < 64; off <<= 1) {
              unsigned long long o = __shfl_xor(mn, off);
              mn = (o < mn) ? o : mn;
            }
            if (ln == 0) cand[wv][r] = mn;
            last = mn;
#pragma unroll
            for (int chk = 0; chk < CAPW / 64; ++chk)
              if (c[chk] == mn) c[chk] = ~0ull;
          }
          tot = KNB;
          taukey = last;
        }
        int flat = b2 + ln;
        unsigned long long key = ~0ull;
        bool ok = false;
        if (flat < T) {
          // binary search: largest l with ps[l] <= flat (zero-len lanes
          // auto-skipped since ps[l]==ps[l+1])
          int lo = 0;
#pragma unroll
          for (int step = 32; step > 0; step >>= 1) {
            int mid = lo + step;
            if (mid <= 63 && (int)rps[wv][mid] <= flat) lo = mid;
          }
          int o = flat - (int)rps[wv][lo];
          uint32_t sa = rsA[wv][lo], la = rlA[wv][lo];
          int p = (o < (int)la) ? (int)(sa + o)
                                : (int)(rsB[wv][lo] + (uint32_t)(o - (int)la));
          float4 pj = spos4[p];
          float dot = fmaf(qp.x, pj.x, fmaf(qp.y, pj.y, qp.z * pj.z));
          float tt  = fmaf(-2.f, dot, pj.w);
          float d2  = fmaxf(qp.w + tt, 0.f);
          key = ((unsigned long long)__float_as_uint(d2) << 32) |
                (uint32_t)sid[p];
          ok = key < taukey;
        }
        unsigned long long bm = __ballot(ok);
        int pos = __popcll(bm & ((1ull << ln) - 1ull));
        if (ok) cand[wv][tot + pos] = key;
        tot += __popcll(bm);
      }
    }
    // termination: distance from q to unexplored region (clamped side = inf)
    if (tot >= KNB) {
      float fx = qp.x - GORIG, fy = qp.y - GORIG, fz = qp.z - GORIG;
      float r = 3.0e38f;
      if (cqx - s > 0)      r = fminf(r, fx - (float)(cqx - s) * GEDGE);
      if (cqx + s < GD - 1) r = fminf(r, (float)(cqx + s + 1) * GEDGE - fx);
      if (cqy - s > 0)      r = fminf(r, fy - (float)(cqy - s) * GEDGE);
      if (cqy + s < GD - 1) r = fminf(r, (float)(cqy + s + 1) * GEDGE - fy);
      if (cqz - s > 0)      r = fminf(r, fz - (float)(cqz - s) * GEDGE);
      if (cqz + s < GD - 1) r = fminf(r, (float)(cqz + s + 1) * GEDGE - fz);
      float r2 = (r > 1.0e19f) ? 3.0e38f : r * r;
      int cnt = 0;
      for (int chk = 0; chk * 64 < tot; ++chk) {
        int slot = chk * 64 + ln;
        unsigned long long key = cand[wv][slot];
        float d2v = __uint_as_float((uint32_t)(key >> 32));
        cnt += __popcll(__ballot(slot < tot && d2v <= r2));
      }
      if (cnt >= KNB) done = true;
    }
    s_lo = s;
  }

  // extraction (proven machinery)
  int nc = tot;
  unsigned long long c[CAPW / 64];
#pragma unroll
  for (int chk = 0; chk < CAPW / 64; ++chk) {
    int slot = chk * 64 + ln;
    unsigned long long k2 = cand[wv][slot];
    c[chk] = (slot < nc) ? k2 : ~0ull;
  }
#pragma unroll
  for (int r = 0; r < KNB; ++r) {
    unsigned long long mn = c[0];
#pragma unroll
    for (int chk = 1; chk < CAPW / 64; ++chk) mn = (c[chk] < mn) ? c[chk] : mn;
#pragma unroll
    for (int off = 1; off < 64; off <<= 1) {
      unsigned long long o = __shfl_xor(mn, off);
      mn = (o < mn) ? o : mn;
    }
    if (ln == 0) nbr[m * KNB + r] = (int)(uint32_t)mn;
#pragma unroll
    for (int chk = 0; chk < CAPW / 64; ++chk)
      if (c[chk] == mn) c[chk] = ~0ull;
  }
}

// ---------------------------------------------------------------------------
// mid: 8 queries / 256-thread block (unchanged from passing version).
// ---------------------------------------------------------------------------
__global__ __launch_bounds__(256) void mid_kernel(
    const unsigned short* __restrict__ xb, const float4* __restrict__ pos4,
    const int* __restrict__ idx, const float* __restrict__ W_pos,
    const float* __restrict__ b_pos, const unsigned short* __restrict__ Wt,
    const float* __restrict__ b_att, const int* __restrict__ nbr,
    float* __restrict__ aggr, int M) {
  __shared__ __align__(16) unsigned short fijb[8][16][136];
  __shared__ int nbr_s[128];
  __shared__ float4 qpos_s[8];

  const int tid = threadIdx.x;
  const int wid = tid >> 6, lane = tid & 63;
  const int col = lane & 15, quad = lane >> 4;
  const int b = blockIdx.x;

  if (tid < 128) {
    int mq = b * 8 + (tid >> 4); if (mq >= M) mq = M - 1;
    nbr_s[tid] = nbr[mq * 16 + (tid & 15)];
  }
  if (tid < 8) {
    int mq = b * 8 + tid; if (mq >= M) mq = M - 1;
    qpos_s[tid] = pos4[idx[mq]];
  }
  float wp[10];
#pragma unroll
  for (int t = 0; t < 10; ++t) wp[t] = W_pos[t * 64 + lane];
  float bp = b_pos[lane];
  __syncthreads();

  {
    int rr = tid >> 1, h = tid & 1;
    int jn = nbr_s[rr];
    const short8* src = (const short8*)(xb + ((size_t)jn << 6) + (h << 5));
    short8 v0 = src[0], v1 = src[1], v2 = src[2], v3 = src[3];
    short8* dst = (short8*)&fijb[rr >> 4][rr & 15][h * 32];
    dst[0] = v0; dst[1] = v1; dst[2] = v2; dst[3] = v3;
  }
#pragma unroll
  for (int qi = 0; qi < 2; ++qi) {
    int q = wid * 2 + qi;
    float4 qp = qpos_s[q];
#pragma unroll 4
    for (int k = 0; k < 16; ++k) {
      int jn = nbr_s[q * 16 + k];
      float4 pj = pos4[jn];
      float vx = qp.x - pj.x, vy = qp.y - pj.y, vz = qp.z - pj.z;
      float dd = sqrtf(fmaf(vx, vx, fmaf(vy, vy, vz * vz)));
      float r = bp;
      r = fmaf(qp.x, wp[0], r); r = fmaf(qp.y, wp[1], r); r = fmaf(qp.z, wp[2], r);
      r = fmaf(pj.x, wp[3], r); r = fmaf(pj.y, wp[4], r); r = fmaf(pj.z, wp[5], r);
      r = fmaf(vx, wp[6], r);  r = fmaf(vy, wp[7], r);  r = fmaf(vz, wp[8], r);
      r = fmaf(dd, wp[9], r);
      r = fmaxf(r, 0.f);
      fijb[q][k][64 + lane] = f2bf(r);
    }
  }
  __syncthreads();

#pragma unroll 1
  for (int qi = 0; qi < 2; ++qi) {
    int q = wid * 2 + qi;
    int mq = b * 8 + q;

    short8 af[4];
#pragma unroll
    for (int cs = 0; cs < 4; ++cs)
      af[cs] = *(const short8*)&fijb[q][col][cs * 32 + quad * 8];

    floatx4 acc[8];
#pragma unroll
    for (int ft = 0; ft < 8; ++ft) {
      float bav = b_att[ft * 16 + col];
      floatx4 a = {bav, bav, bav, bav};
#pragma unroll
      for (int cs = 0; cs < 4; ++cs) {
        short8 bfrag =
            *(const short8*)&Wt[(ft * 16 + col) * 128 + cs * 32 + quad * 8];
        a = __builtin_amdgcn_mfma_f32_16x16x32_bf16(af[cs], bfrag, a, 0, 0, 0);
      }
      acc[ft] = a;
    }

    float rowmax[4], rowinv[4];
#pragma unroll
    for (int r = 0; r < 4; ++r) {
      float mx = acc[0][r];
#pragma unroll
      for (int ft = 1; ft < 8; ++ft) mx = fmaxf(mx, acc[ft][r]);
      mx = fmaxf(mx, __shfl_xor(mx, 1));
      mx = fmaxf(mx, __shfl_xor(mx, 2));
      mx = fmaxf(mx, __shfl_xor(mx, 4));
      mx = fmaxf(mx, __shfl_xor(mx, 8));
      float sm = 0.f;
#pragma unroll
      for (int ft = 0; ft < 8; ++ft) sm += __expf(acc[ft][r] - mx);
      sm += __shfl_xor(sm, 1);
      sm += __shfl_xor(sm, 2);
      sm += __shfl_xor(sm, 4);
      sm += __shfl_xor(sm, 8);
      rowmax[r] = mx;
      rowinv[r] = 1.0f / sm;
    }

#pragma unroll
    for (int ft = 0; ft < 8; ++ft) {
      float ap = 0.f;
#pragma unroll
      for (int r = 0; r < 4; ++r) {
        float s = __expf(acc[ft][r] - rowmax[r]) * rowinv[r];
        float fv = bf2f(fijb[q][quad * 4 + r][ft * 16 + col]);
        ap = fmaf(s, fv, ap);
      }
      ap += __shfl_xor(ap, 16);
      ap += __shfl_xor(ap, 32);
      if (quad == 0 && mq < M)
        aggr[mq * 128 + ft * 16 + col] = ap * (1.0f / 16.0f);
    }
  }
}

// ---------------------------------------------------------------------------
// out = relu(aggr @ W_glob + b_glob)
// ---------------------------------------------------------------------------
__global__ __launch_bounds__(256) void out_kernel(
    const float* __restrict__ aggr, const float* __restrict__ W_glob,
    const float* __restrict__ b_glob, float* __restrict__ out, int M) {
  __shared__ float ag[16][128];
  const int tid = threadIdx.x;
  const int mbase = blockIdx.x * 16;
  for (int s = tid; s < 16 * 128; s += 256) {
    int r = s >> 7, cc = s & 127;
    int m = mbase + r;
    ((float*)ag)[s] = (m < M) ? aggr[m * 128 + cc] : 0.0f;
  }
  __syncthreads();
  const int f = tid & 127, h = tid >> 7;
  float acc[8];
  float bg = b_glob[f];
#pragma unroll
  for (int i = 0; i < 8; ++i) acc[i] = bg;
  for (int c = 0; c < 128; c += 4) {
    float w0 = W_glob[(c + 0) * 128 + f];
    float w1 = W_glob[(c + 1) * 128 + f];
    float w2 = W_glob[(c + 2) * 128 + f];
    float w3 = W_glob[(c + 3) * 128 + f];
#pragma unroll
    for (int i = 0; i < 8; ++i) {
      const floatx4 a4 = *(const floatx4*)&ag[h * 8 + i][c];
      acc[i] += a4[0] * w0 + a4[1] * w1 + a4[2] * w2 + a4[3] * w3;
    }
  }
#pragma unroll
  for (int i = 0; i < 8; ++i) {
    int m = mbase + h * 8 + i;
    if (m < M) out[m * 128 + f] = fmaxf(acc[i], 0.0f);
  }
}

// ---------------------------------------------------------------------------
extern "C" void kernel_launch(void* const* d_in, const int* in_sizes, int n_in,
                              void* d_out, int out_size, void* d_ws,
                              size_t ws_size, hipStream_t stream) {
  const float* x      = (const float*)d_in[0];
  const float* pos    = (const float*)d_in[1];
  const int*   idx    = (const int*)d_in[2];
  const float* W_pos  = (const float*)d_in[3];
  const float* b_pos  = (const float*)d_in[4];
  const float* W_att  = (const float*)d_in[5];
  const float* b_att  = (const float*)d_in[6];
  const float* W_glob = (const float*)d_in[7];
  const float* b_glob = (const float*)d_in[8];
  float* out = (float*)d_out;

  const int N = in_sizes[1] / 3;
  const int M = in_sizes[2];

  char* ws = (char*)d_ws;
  size_t o = 0;
  float4* pos4 = (float4*)(ws + o);               o += ((size_t)N * 16 + 255) & ~(size_t)255;
  unsigned short* xb = (unsigned short*)(ws + o); o += ((size_t)N * 128 + 255) & ~(size_t)255;
  unsigned short* Wt = (unsigned short*)(ws + o); o += (128 * 128 * 2 + 255) & ~(size_t)255;
  int* nbr = (int*)(ws + o);                      o += (((size_t)M * KNB * 4) + 255) & ~(size_t)255;
  int* ptcell = (int*)(ws + o);                   o += (((size_t)N * 4) + 255) & ~(size_t)255;
  int* count = (int*)(ws + o);                    o += ((size_t)GTOT * 4 + 255) & ~(size_t)255;
  int* cursor = (int*)(ws + o);                   o += ((size_t)GTOT * 4 + 255) & ~(size_t)255;
  int* cell_start = (int*)(ws + o);               o += ((size_t)(GTOT + 1) * 4 + 255) & ~(size_t)255;
  int* partial = (int*)(ws + o);                  o += (1024 * 4 + 255) & ~(size_t)255;
  float4* spos4 = (float4*)(ws + o);              o += ((size_t)N * 16 + 255) & ~(size_t)255;
  int* sid = (int*)(ws + o);                      o += (((size_t)N * 4) + 255) & ~(size_t)255;
  float* aggr = (float*)(ws + o);                 o += ((size_t)M * 128 * 4 + 255) & ~(size_t)255;

  zero_kernel<<<GTOT / 1024, 256, 0, stream>>>(count);

  int prep_ids = N * 8 + N + 128 * 128;
  prep_kernel<<<(prep_ids + 255) / 256, 256, 0, stream>>>(
      x, pos, W_att, xb, pos4, Wt, ptcell, count, N);

  scan1<<<GTOT / 256, 256, 0, stream>>>(count, partial);
  scan2<<<1, 256, 0, stream>>>(partial, cell_start);
  scan3<<<GTOT / 256, 256, 0, stream>>>(count, partial, cell_start, cursor);

  scatter_kernel<<<(N + 255) / 256, 256, 0, stream>>>(pos4, ptcell, cursor,
                                                      spos4, sid, N);

  knn_grid<<<(M + 3) / 4, 256, 0, stream>>>(pos4, spos4, sid, cell_start, idx,
                                            nbr, M);

  mid_kernel<<<(M + 7) / 8, 256, 0, stream>>>(xb, pos4, idx, W_pos, b_pos, Wt,
                                              b_att, nbr, aggr, M);
  out_kernel<<<(M + 15) / 16, 256, 0, stream>>>(aggr, W_glob, b_glob, out, M);
}

// Round 10
// 218.588 us; speedup vs baseline: 1.2203x; 1.2203x over previous
//
#include <hip/hip_runtime.h>
#include <stdint.h>

#define KNB     16
#define GD      64                  // grid cells per axis
#define GTOT    (GD * GD * GD)      // 262144 cells
#define GORIG   (-6.5f)
#define GEDGE   0.203125f           // 13.0 / 64
#define GINV    (1.0f / GEDGE)
#define CAPW    320                 // per-query candidate capacity (5 x 64)
#define PROBE_T 48                  // min cube count for round-1 (>= KNB)

typedef short short8 __attribute__((ext_vector_type(8)));
typedef float floatx4 __attribute__((ext_vector_type(4)));

__device__ __forceinline__ unsigned short f2bf(float x) {
  union { float f; uint32_t u; } v; v.f = x;
  uint32_t u = v.u + 0x7FFFu + ((v.u >> 16) & 1u);   // RNE
  return (unsigned short)(u >> 16);
}
__device__ __forceinline__ float bf2f(unsigned short b) {
  return __uint_as_float(((uint32_t)b) << 16);
}
__device__ __forceinline__ int cellco(float v) {
  int c = (int)floorf((v - GORIG) * GINV);
  return c < 0 ? 0 : (c > GD - 1 ? GD - 1 : c);
}

// ---------------------------------------------------------------------------
// zero: count[GTOT] = 0  (must run before prep's atomics, every launch)
// ---------------------------------------------------------------------------
__global__ void zero_kernel(int* __restrict__ count) {
  int i = (blockIdx.x * 256 + threadIdx.x) * 4;
  *(int4*)(count + i) = make_int4(0, 0, 0, 0);
}

// ---------------------------------------------------------------------------
// prep: xb = bf16(x); pos4 = {x,y,z,pp}; ptcell[j] + count atomics; Wt.
// ---------------------------------------------------------------------------
__global__ void prep_kernel(const float* __restrict__ x,
                            const float* __restrict__ pos,
                            const float* __restrict__ W_att,
                            unsigned short* __restrict__ xb,
                            float4* __restrict__ pos4,
                            unsigned short* __restrict__ Wt,
                            int* __restrict__ ptcell,
                            int* __restrict__ count, int N) {
  int id = blockIdx.x * 256 + threadIdx.x;
  int nx8 = N * 8;
  if (id < nx8) {
    const float4* src = (const float4*)x + (size_t)id * 2;
    float4 a = src[0], b = src[1];
    short8 v;
    v[0] = (short)f2bf(a.x); v[1] = (short)f2bf(a.y);
    v[2] = (short)f2bf(a.z); v[3] = (short)f2bf(a.w);
    v[4] = (short)f2bf(b.x); v[5] = (short)f2bf(b.y);
    v[6] = (short)f2bf(b.z); v[7] = (short)f2bf(b.w);
    *(short8*)(xb + (size_t)id * 8) = v;
  } else if (id < nx8 + N) {
    int j = id - nx8;
    float px = pos[3 * j], py = pos[3 * j + 1], pz = pos[3 * j + 2];
    float pp = fmaf(px, px, fmaf(py, py, pz * pz));
    pos4[j] = make_float4(px, py, pz, pp);
    int cid = (cellco(pz) * GD + cellco(py)) * GD + cellco(px);
    ptcell[j] = cid;
    atomicAdd(&count[cid], 1);
  } else if (id < nx8 + N + 128 * 128) {
    int t = id - nx8 - N;
    int c = t >> 7, f = t & 127;
    Wt[f * 128 + c] = f2bf(W_att[t]);
  }
}

// ---------------------------------------------------------------------------
// two-level exclusive scan of count[GTOT] -> cell_start / cursor
// ---------------------------------------------------------------------------
__global__ __launch_bounds__(256) void scan1(const int* __restrict__ count,
                                             int* __restrict__ partial) {
  int b = blockIdx.x, t = threadIdx.x;
  int v = count[b * 256 + t];
#pragma unroll
  for (int off = 1; off < 64; off <<= 1) v += __shfl_xor(v, off);
  __shared__ int ws_[4];
  if ((t & 63) == 0) ws_[t >> 6] = v;
  __syncthreads();
  if (t == 0) partial[b] = ws_[0] + ws_[1] + ws_[2] + ws_[3];
}

__global__ __launch_bounds__(256) void scan2(int* __restrict__ partial,
                                             int* __restrict__ cell_start) {
  int t = threadIdx.x;
  int v0 = partial[t * 4], v1 = partial[t * 4 + 1];
  int v2 = partial[t * 4 + 2], v3 = partial[t * 4 + 3];
  int s1 = v0 + v1, s2 = s1 + v2, s3 = s2 + v3;
  int x = s3;
  int lane = t & 63, wv = t >> 6;
#pragma unroll
  for (int off = 1; off < 64; off <<= 1) {
    int y = __shfl_up(x, off);
    if (lane >= off) x += y;
  }
  __shared__ int wsum[4];
  if (lane == 63) wsum[wv] = x;
  __syncthreads();
  int base = 0;
  for (int k = 0; k < wv; ++k) base += wsum[k];
  int excl = base + x - s3;
  partial[t * 4]     = excl;
  partial[t * 4 + 1] = excl + v0;
  partial[t * 4 + 2] = excl + s1;
  partial[t * 4 + 3] = excl + s2;
  if (t == 255) cell_start[GTOT] = excl + s3;   // = N
}

__global__ __launch_bounds__(256) void scan3(const int* __restrict__ count,
                                             const int* __restrict__ partial,
                                             int* __restrict__ cell_start,
                                             int* __restrict__ cursor) {
  int b = blockIdx.x, t = threadIdx.x;
  int v = count[b * 256 + t];
  int x = v;
  int lane = t & 63, wv = t >> 6;
#pragma unroll
  for (int off = 1; off < 64; off <<= 1) {
    int y = __shfl_up(x, off);
    if (lane >= off) x += y;
  }
  __shared__ int wsum[4];
  if (lane == 63) wsum[wv] = x;
  __syncthreads();
  int base = partial[b];
  for (int k = 0; k < wv; ++k) base += wsum[k];
  int excl = base + x - v;
  cell_start[b * 256 + t] = excl;
  cursor[b * 256 + t] = excl;
}

// ---------------------------------------------------------------------------
// scatter: points into cell-sorted order (spos4 + original index sid)
// ---------------------------------------------------------------------------
__global__ void scatter_kernel(const float4* __restrict__ pos4,
                               const int* __restrict__ ptcell,
                               int* __restrict__ cursor,
                               float4* __restrict__ spos4,
                               int* __restrict__ sid, int N) {
  int j = blockIdx.x * 256 + threadIdx.x;
  if (j >= N) return;
  int cid = ptcell[j];
  int slot = atomicAdd(&cursor[cid], 1);
  spos4[slot] = pos4[j];
  sid[slot] = j;
}

// ---------------------------------------------------------------------------
// summed-volume table V (3D inclusive prefix of per-cell counts), 3 passes.
// One wave per line; 4096 lines per axis pass.
// ---------------------------------------------------------------------------
__global__ __launch_bounds__(256) void vscan_x(const int* __restrict__ count,
                                               int* __restrict__ V) {
  int row = blockIdx.x * 4 + (threadIdx.x >> 6);
  int ln = threadIdx.x & 63;
  int i = row * GD + ln;
  int v = count[i];
#pragma unroll
  for (int off = 1; off < 64; off <<= 1) {
    int y = __shfl_up(v, off);
    if (ln >= off) v += y;
  }
  V[i] = v;
}

__global__ __launch_bounds__(256) void vscan_y(int* __restrict__ V) {
  int pair = blockIdx.x * 4 + (threadIdx.x >> 6);   // z*64 + x
  int z = pair >> 6, x = pair & 63;
  int ln = threadIdx.x & 63;                        // y
  int i = (z * GD + ln) * GD + x;
  int v = V[i];
#pragma unroll
  for (int off = 1; off < 64; off <<= 1) {
    int y = __shfl_up(v, off);
    if (ln >= off) v += y;
  }
  V[i] = v;
}

__global__ __launch_bounds__(256) void vscan_z(int* __restrict__ V) {
  int pair = blockIdx.x * 4 + (threadIdx.x >> 6);   // y*64 + x
  int ln = threadIdx.x & 63;                        // z
  int i = ln * GD * GD + pair;
  int v = V[i];
#pragma unroll
  for (int off = 1; off < 64; off <<= 1) {
    int y = __shfl_up(v, off);
    if (ln >= off) v += y;
  }
  V[i] = v;
}

// ---------------------------------------------------------------------------
// top16_lds: exact top-16 of candw[0..tot) -> candw[0..16) in rank order;
// returns the 16th (largest) key. Requires tot >= KNB. Dynamic chunk count.
// ---------------------------------------------------------------------------
__device__ __forceinline__ unsigned long long top16_lds(
    unsigned long long* candw, int tot, int ln) {
  int nch = (tot + 63) >> 6;
  unsigned long long mykey = ~0ull, last = 0;
  for (int r = 0; r < KNB; ++r) {
    unsigned long long mn = ~0ull;
    for (int chk = 0; chk < nch; ++chk) {
      int slot = chk * 64 + ln;
      if (slot < tot) {
        unsigned long long k = candw[slot];
        mn = (k < mn) ? k : mn;
      }
    }
#pragma unroll
    for (int off = 1; off < 64; off <<= 1) {
      unsigned long long o = __shfl_xor(mn, off);
      mn = (o < mn) ? o : mn;
    }
    for (int chk = 0; chk < nch; ++chk) {
      int slot = chk * 64 + ln;
      if (slot < tot && candw[slot] == mn) candw[slot] = ~0ull;
    }
    if (ln == r) mykey = mn;
    last = mn;
  }
  if (ln < KNB) candw[ln] = mykey;
  return last;
}

// ---------------------------------------------------------------------------
// drain_annulus: drain all cells with Chebyshev radius in (slo, shi] around
// (cqx,cqy,cqz), clamped to grid. Rows with max(|dz|,|dy|) > slo are full
// x-rows [cqx-shi, cqx+shi]; inner rows contribute two x-segments excluding
// the already-drained cube(slo). Flat cooperative drain (R8-proven): wave
// prefix-sum of row lengths + 6-step binary search per point chunk.
// Compacts to exact top-16 (taukey) before any chunk could overflow CAPW.
// ---------------------------------------------------------------------------
__device__ __forceinline__ void drain_annulus(
    const float4* __restrict__ spos4, const int* __restrict__ sid,
    const int* __restrict__ cell_start, unsigned long long* candw,
    uint32_t* rsAw, uint32_t* rlAw, uint32_t* rsBw, uint32_t* rpsw,
    float4 qp, int cqx, int cqy, int cqz, int slo, int shi, int ln,
    int& tot, unsigned long long& taukey) {
  const int z0 = (cqz - shi < 0) ? 0 : cqz - shi;
  const int z1 = (cqz + shi > GD - 1) ? GD - 1 : cqz + shi;
  const int y0 = (cqy - shi < 0) ? 0 : cqy - shi;
  const int y1 = (cqy + shi > GD - 1) ? GD - 1 : cqy + shi;
  const int wy = y1 - y0 + 1;
  const int npair = (z1 - z0 + 1) * wy;
  for (int base = 0; base < npair; base += 64) {
    int i = base + ln;
    int stA = 0, lA = 0, stB = 0, lB = 0;
    if (i < npair) {
      int zz = z0 + i / wy;
      int yy = y0 + (i - (i / wy) * wy);
      int dz = zz - cqz, dy = yy - cqy;
      int az = dz < 0 ? -dz : dz, ay = dy < 0 ? -dy : dy;
      int ch = az > ay ? az : ay;
      int rowbase = (zz * GD + yy) * GD;
      if (ch > slo) {
        int x0 = cqx - shi; if (x0 < 0) x0 = 0;
        int x1 = cqx + shi; if (x1 > GD - 1) x1 = GD - 1;
        stA = cell_start[rowbase + x0];
        lA  = cell_start[rowbase + x1 + 1] - stA;
      } else {
        int xl0 = cqx - shi; if (xl0 < 0) xl0 = 0;
        int xl1 = cqx - slo - 1;
        if (xl1 >= xl0) {
          stA = cell_start[rowbase + xl0];
          lA  = cell_start[rowbase + xl1 + 1] - stA;
        }
        int xr0 = cqx + slo + 1;
        int xr1 = cqx + shi; if (xr1 > GD - 1) xr1 = GD - 1;
        if (xr1 >= xr0) {
          stB = cell_start[rowbase + xr0];
          lB  = cell_start[rowbase + xr1 + 1] - stB;
        }
      }
    }
    int len = lA + lB;
    int xinc = len;
#pragma unroll
    for (int off = 1; off < 64; off <<= 1) {
      int y = __shfl_up(xinc, off);
      if (ln >= off) xinc += y;
    }
    int T = __shfl(xinc, 63);
    if (T == 0) continue;
    rpsw[ln] = (uint32_t)(xinc - len);   // exclusive prefix
    rsAw[ln] = (uint32_t)stA;
    rlAw[ln] = (uint32_t)lA;
    rsBw[ln] = (uint32_t)stB;
    for (int b2 = 0; b2 < T; b2 += 64) {
      if (tot + 64 > CAPW) {             // overflow-proof compaction
        taukey = top16_lds(candw, tot, ln);
        tot = KNB;
      }
      int flat = b2 + ln;
      unsigned long long key = ~0ull;
      bool ok = false;
      if (flat < T) {
        int lo = 0;
#pragma unroll
        for (int step = 32; step > 0; step >>= 1) {
          int mid = lo + step;
          if (mid <= 63 && (int)rpsw[mid] <= flat) lo = mid;
        }
        int o = flat - (int)rpsw[lo];
        uint32_t sa = rsAw[lo], la = rlAw[lo];
        int p = (o < (int)la) ? (int)(sa + o)
                              : (int)(rsBw[lo] + (uint32_t)(o - (int)la));
        float4 pj = spos4[p];
        float dot = fmaf(qp.x, pj.x, fmaf(qp.y, pj.y, qp.z * pj.z));
        float tt  = fmaf(-2.f, dot, pj.w);
        float d2  = fmaxf(qp.w + tt, 0.f);
        key = ((unsigned long long)__float_as_uint(d2) << 32) |
              (uint32_t)sid[p];
        ok = key < taukey;
      }
      unsigned long long bm = __ballot(ok);
      int pos = __popcll(bm & ((1ull << ln) - 1ull));
      if (ok) candw[tot + pos] = key;
      tot += __popcll(bm);
    }
  }
}

// ---------------------------------------------------------------------------
// knn_grid (R10): one wave per query, NO shell walk.
// 1) lane-parallel probe: lane s counts cube(s) via 8 summed-volume lookups;
//    ballot -> minimal s0 with count >= PROBE_T (>= KNB, so >= 16 neighbors
//    incl. self exist in cube(s0)).
// 2) round 1: drain cube(s0) (slo=-1); compact -> exact top-16, d16.
// 3) s1 = minimal s with r_expl(s)^2 >= d16^2 (same r_expl formula as the
//    proven termination check; grid-clamped sides = inf). Round 2: drain
//    annulus (s0, s1] with taukey filter. Unexplored points have
//    d2 >= r_expl(s1)^2 >= d16^2 -- identical guarantee to the proven
//    "16 stored within r_expl" termination. Final compact -> nbr.
// ---------------------------------------------------------------------------
__global__ __launch_bounds__(256) void knn_grid(
    const float4* __restrict__ pos4, const float4* __restrict__ spos4,
    const int* __restrict__ sid, const int* __restrict__ cell_start,
    const int* __restrict__ V, const int* __restrict__ idx,
    int* __restrict__ nbr, int M) {
  __shared__ unsigned long long cand[4][CAPW];
  __shared__ uint32_t rsA[4][64], rlA[4][64], rsB[4][64], rps[4][64];
  const int tid = threadIdx.x, wv = tid >> 6, ln = tid & 63;
  const int m = blockIdx.x * 4 + wv;
  if (m >= M) return;

  const float4 qp = pos4[idx[m]];
  const int cqx = cellco(qp.x), cqy = cellco(qp.y), cqz = cellco(qp.z);

  // --- lane-parallel minimal-cube probe via summed-volume table ---
  int s0;
  {
    int s = ln;
    int xh = cqx + s > GD - 1 ? GD - 1 : cqx + s;
    int yh = cqy + s > GD - 1 ? GD - 1 : cqy + s;
    int zh = cqz + s > GD - 1 ? GD - 1 : cqz + s;
    int xm = cqx - s - 1, ym = cqy - s - 1, zm = cqz - s - 1;
    int c = V[(zh * GD + yh) * GD + xh];
    if (zm >= 0) c -= V[(zm * GD + yh) * GD + xh];
    if (ym >= 0) c -= V[(zh * GD + ym) * GD + xh];
    if (xm >= 0) c -= V[(zh * GD + yh) * GD + xm];
    if (zm >= 0 && ym >= 0) c += V[(zm * GD + ym) * GD + xh];
    if (zm >= 0 && xm >= 0) c += V[(zm * GD + yh) * GD + xm];
    if (ym >= 0 && xm >= 0) c += V[(zh * GD + ym) * GD + xm];
    if (zm >= 0 && ym >= 0 && xm >= 0) c -= V[(zm * GD + ym) * GD + xm];
    unsigned long long bm = __ballot(c >= PROBE_T);
    s0 = __ffsll((unsigned long long)bm) - 1;   // bit 63 always set (c = N)
  }

  // --- round 1: drain cube(s0), compact to exact top-16 ---
  int tot = 0;
  unsigned long long taukey = ~0ull;
  drain_annulus(spos4, sid, cell_start, &cand[wv][0], &rsA[wv][0],
                &rlA[wv][0], &rsB[wv][0], &rps[wv][0], qp, cqx, cqy, cqz,
                -1, s0, ln, tot, taukey);
  taukey = top16_lds(&cand[wv][0], tot, ln);
  tot = KNB;
  float d16sq = __uint_as_float((uint32_t)(taukey >> 32));

  // --- s1: minimal radius whose guaranteed-explored ball covers d16 ---
  int s1 = s0;
  {
    float fx = qp.x - GORIG, fy = qp.y - GORIG, fz = qp.z - GORIG;
    while (s1 < GD - 1) {
      float r = 3.0e38f;
      if (cqx - s1 > 0)      r = fminf(r, fx - (float)(cqx - s1) * GEDGE);
      if (cqx + s1 < GD - 1) r = fminf(r, (float)(cqx + s1 + 1) * GEDGE - fx);
      if (cqy - s1 > 0)      r = fminf(r, fy - (float)(cqy - s1) * GEDGE);
      if (cqy + s1 < GD - 1) r = fminf(r, (float)(cqy + s1 + 1) * GEDGE - fy);
      if (cqz - s1 > 0)      r = fminf(r, fz - (float)(cqz - s1) * GEDGE);
      if (cqz + s1 < GD - 1) r = fminf(r, (float)(cqz + s1 + 1) * GEDGE - fz);
      float r2 = (r > 1.0e19f) ? 3.0e38f : r * r;
      if (r2 >= d16sq) break;
      ++s1;
    }
  }

  // --- round 2: drain annulus (s0, s1] with taukey filter ---
  if (s1 > s0) {
    drain_annulus(spos4, sid, cell_start, &cand[wv][0], &rsA[wv][0],
                  &rlA[wv][0], &rsB[wv][0], &rps[wv][0], qp, cqx, cqy, cqz,
                  s0, s1, ln, tot, taukey);
    if (tot > KNB) (void)top16_lds(&cand[wv][0], tot, ln);
  }

  if (ln < KNB) nbr[m * KNB + ln] = (int)(uint32_t)cand[wv][ln];
}

// ---------------------------------------------------------------------------
// mid: 8 queries / 256-thread block (unchanged from passing version).
// ---------------------------------------------------------------------------
__global__ __launch_bounds__(256) void mid_kernel(
    const unsigned short* __restrict__ xb, const float4* __restrict__ pos4,
    const int* __restrict__ idx, const float* __restrict__ W_pos,
    const float* __restrict__ b_pos, const unsigned short* __restrict__ Wt,
    const float* __restrict__ b_att, const int* __restrict__ nbr,
    float* __restrict__ aggr, int M) {
  __shared__ __align__(16) unsigned short fijb[8][16][136];
  __shared__ int nbr_s[128];
  __shared__ float4 qpos_s[8];

  const int tid = threadIdx.x;
  const int wid = tid >> 6, lane = tid & 63;
  const int col = lane & 15, quad = lane >> 4;
  const int b = blockIdx.x;

  if (tid < 128) {
    int mq = b * 8 + (tid >> 4); if (mq >= M) mq = M - 1;
    nbr_s[tid] = nbr[mq * 16 + (tid & 15)];
  }
  if (tid < 8) {
    int mq = b * 8 + tid; if (mq >= M) mq = M - 1;
    qpos_s[tid] = pos4[idx[mq]];
  }
  float wp[10];
#pragma unroll
  for (int t = 0; t < 10; ++t) wp[t] = W_pos[t * 64 + lane];
  float bp = b_pos[lane];
  __syncthreads();

  {
    int rr = tid >> 1, h = tid & 1;
    int jn = nbr_s[rr];
    const short8* src = (const short8*)(xb + ((size_t)jn << 6) + (h << 5));
    short8 v0 = src[0], v1 = src[1], v2 = src[2], v3 = src[3];
    short8* dst = (short8*)&fijb[rr >> 4][rr & 15][h * 32];
    dst[0] = v0; dst[1] = v1; dst[2] = v2; dst[3] = v3;
  }
#pragma unroll
  for (int qi = 0; qi < 2; ++qi) {
    int q = wid * 2 + qi;
    float4 qp = qpos_s[q];
#pragma unroll 4
    for (int k = 0; k < 16; ++k) {
      int jn = nbr_s[q * 16 + k];
      float4 pj = pos4[jn];
      float vx = qp.x - pj.x, vy = qp.y - pj.y, vz = qp.z - pj.z;
      float dd = sqrtf(fmaf(vx, vx, fmaf(vy, vy, vz * vz)));
      float r = bp;
      r = fmaf(qp.x, wp[0], r); r = fmaf(qp.y, wp[1], r); r = fmaf(qp.z, wp[2], r);
      r = fmaf(pj.x, wp[3], r); r = fmaf(pj.y, wp[4], r); r = fmaf(pj.z, wp[5], r);
      r = fmaf(vx, wp[6], r);  r = fmaf(vy, wp[7], r);  r = fmaf(vz, wp[8], r);
      r = fmaf(dd, wp[9], r);
      r = fmaxf(r, 0.f);
      fijb[q][k][64 + lane] = f2bf(r);
    }
  }
  __syncthreads();

#pragma unroll 1
  for (int qi = 0; qi < 2; ++qi) {
    int q = wid * 2 + qi;
    int mq = b * 8 + q;

    short8 af[4];
#pragma unroll
    for (int cs = 0; cs < 4; ++cs)
      af[cs] = *(const short8*)&fijb[q][col][cs * 32 + quad * 8];

    floatx4 acc[8];
#pragma unroll
    for (int ft = 0; ft < 8; ++ft) {
      float bav = b_att[ft * 16 + col];
      floatx4 a = {bav, bav, bav, bav};
#pragma unroll
      for (int cs = 0; cs < 4; ++cs) {
        short8 bfrag =
            *(const short8*)&Wt[(ft * 16 + col) * 128 + cs * 32 + quad * 8];
        a = __builtin_amdgcn_mfma_f32_16x16x32_bf16(af[cs], bfrag, a, 0, 0, 0);
      }
      acc[ft] = a;
    }

    float rowmax[4], rowinv[4];
#pragma unroll
    for (int r = 0; r < 4; ++r) {
      float mx = acc[0][r];
#pragma unroll
      for (int ft = 1; ft < 8; ++ft) mx = fmaxf(mx, acc[ft][r]);
      mx = fmaxf(mx, __shfl_xor(mx, 1));
      mx = fmaxf(mx, __shfl_xor(mx, 2));
      mx = fmaxf(mx, __shfl_xor(mx, 4));
      mx = fmaxf(mx, __shfl_xor(mx, 8));
      float sm = 0.f;
#pragma unroll
      for (int ft = 0; ft < 8; ++ft) sm += __expf(acc[ft][r] - mx);
      sm += __shfl_xor(sm, 1);
      sm += __shfl_xor(sm, 2);
      sm += __shfl_xor(sm, 4);
      sm += __shfl_xor(sm, 8);
      rowmax[r] = mx;
      rowinv[r] = 1.0f / sm;
    }

#pragma unroll
    for (int ft = 0; ft < 8; ++ft) {
      float ap = 0.f;
#pragma unroll
      for (int r = 0; r < 4; ++r) {
        float s = __expf(acc[ft][r] - rowmax[r]) * rowinv[r];
        float fv = bf2f(fijb[q][quad * 4 + r][ft * 16 + col]);
        ap = fmaf(s, fv, ap);
      }
      ap += __shfl_xor(ap, 16);
      ap += __shfl_xor(ap, 32);
      if (quad == 0 && mq < M)
        aggr[mq * 128 + ft * 16 + col] = ap * (1.0f / 16.0f);
    }
  }
}

// ---------------------------------------------------------------------------
// out = relu(aggr @ W_glob + b_glob)
// ---------------------------------------------------------------------------
__global__ __launch_bounds__(256) void out_kernel(
    const float* __restrict__ aggr, const float* __restrict__ W_glob,
    const float* __restrict__ b_glob, float* __restrict__ out, int M) {
  __shared__ float ag[16][128];
  const int tid = threadIdx.x;
  const int mbase = blockIdx.x * 16;
  for (int s = tid; s < 16 * 128; s += 256) {
    int r = s >> 7, cc = s & 127;
    int m = mbase + r;
    ((float*)ag)[s] = (m < M) ? aggr[m * 128 + cc] : 0.0f;
  }
  __syncthreads();
  const int f = tid & 127, h = tid >> 7;
  float acc[8];
  float bg = b_glob[f];
#pragma unroll
  for (int i = 0; i < 8; ++i) acc[i] = bg;
  for (int c = 0; c < 128; c += 4) {
    float w0 = W_glob[(c + 0) * 128 + f];
    float w1 = W_glob[(c + 1) * 128 + f];
    float w2 = W_glob[(c + 2) * 128 + f];
    float w3 = W_glob[(c + 3) * 128 + f];
#pragma unroll
    for (int i = 0; i < 8; ++i) {
      const floatx4 a4 = *(const floatx4*)&ag[h * 8 + i][c];
      acc[i] += a4[0] * w0 + a4[1] * w1 + a4[2] * w2 + a4[3] * w3;
    }
  }
#pragma unroll
  for (int i = 0; i < 8; ++i) {
    int m = mbase + h * 8 + i;
    if (m < M) out[m * 128 + f] = fmaxf(acc[i], 0.0f);
  }
}

// ---------------------------------------------------------------------------
extern "C" void kernel_launch(void* const* d_in, const int* in_sizes, int n_in,
                              void* d_out, int out_size, void* d_ws,
                              size_t ws_size, hipStream_t stream) {
  const float* x      = (const float*)d_in[0];
  const float* pos    = (const float*)d_in[1];
  const int*   idx    = (const int*)d_in[2];
  const float* W_pos  = (const float*)d_in[3];
  const float* b_pos  = (const float*)d_in[4];
  const float* W_att  = (const float*)d_in[5];
  const float* b_att  = (const float*)d_in[6];
  const float* W_glob = (const float*)d_in[7];
  const float* b_glob = (const float*)d_in[8];
  float* out = (float*)d_out;

  const int N = in_sizes[1] / 3;
  const int M = in_sizes[2];

  char* ws = (char*)d_ws;
  size_t o = 0;
  float4* pos4 = (float4*)(ws + o);               o += ((size_t)N * 16 + 255) & ~(size_t)255;
  unsigned short* xb = (unsigned short*)(ws + o); o += ((size_t)N * 128 + 255) & ~(size_t)255;
  unsigned short* Wt = (unsigned short*)(ws + o); o += (128 * 128 * 2 + 255) & ~(size_t)255;
  int* nbr = (int*)(ws + o);                      o += (((size_t)M * KNB * 4) + 255) & ~(size_t)255;
  int* ptcell = (int*)(ws + o);                   o += (((size_t)N * 4) + 255) & ~(size_t)255;
  int* count = (int*)(ws + o);                    o += ((size_t)GTOT * 4 + 255) & ~(size_t)255;
  int* cursor = (int*)(ws + o);                   o += ((size_t)GTOT * 4 + 255) & ~(size_t)255;
  int* cell_start = (int*)(ws + o);               o += ((size_t)(GTOT + 1) * 4 + 255) & ~(size_t)255;
  int* V = (int*)(ws + o);                        o += ((size_t)GTOT * 4 + 255) & ~(size_t)255;
  int* partial = (int*)(ws + o);                  o += (1024 * 4 + 255) & ~(size_t)255;
  float4* spos4 = (float4*)(ws + o);              o += ((size_t)N * 16 + 255) & ~(size_t)255;
  int* sid = (int*)(ws + o);                      o += (((size_t)N * 4) + 255) & ~(size_t)255;
  float* aggr = (float*)(ws + o);                 o += ((size_t)M * 128 * 4 + 255) & ~(size_t)255;

  zero_kernel<<<GTOT / 1024, 256, 0, stream>>>(count);

  int prep_ids = N * 8 + N + 128 * 128;
  prep_kernel<<<(prep_ids + 255) / 256, 256, 0, stream>>>(
      x, pos, W_att, xb, pos4, Wt, ptcell, count, N);

  scan1<<<GTOT / 256, 256, 0, stream>>>(count, partial);
  scan2<<<1, 256, 0, stream>>>(partial, cell_start);
  scan3<<<GTOT / 256, 256, 0, stream>>>(count, partial, cell_start, cursor);

  scatter_kernel<<<(N + 255) / 256, 256, 0, stream>>>(pos4, ptcell, cursor,
                                                      spos4, sid, N);

  vscan_x<<<1024, 256, 0, stream>>>(count, V);
  vscan_y<<<1024, 256, 0, stream>>>(V);
  vscan_z<<<1024, 256, 0, stream>>>(V);

  knn_grid<<<(M + 3) / 4, 256, 0, stream>>>(pos4, spos4, sid, cell_start, V,
                                            idx, nbr, M);

  mid_kernel<<<(M + 7) / 8, 256, 0, stream>>>(xb, pos4, idx, W_pos, b_pos, Wt,
                                              b_att, nbr, aggr, M);
  out_kernel<<<(M + 15) / 16, 256, 0, stream>>>(aggr, W_glob, b_glob, out, M);
}

// Round 11
// 208.246 us; speedup vs baseline: 1.2809x; 1.0497x over previous
//
#include <hip/hip_runtime.h>
#include <stdint.h>

#define KNB     16
#define GD      64                  // grid cells per axis
#define GTOT    (GD * GD * GD)      // 262144 cells
#define GORIG   (-6.5f)
#define GEDGE   0.203125f           // 13.0 / 64
#define GINV    (1.0f / GEDGE)
#define CAPW    640                 // per-query candidate capacity (10 x 64)
#define PROBE_T 48                  // min cube count for round-1 (>= KNB)

typedef short short8 __attribute__((ext_vector_type(8)));
typedef float floatx4 __attribute__((ext_vector_type(4)));

__device__ __forceinline__ unsigned short f2bf(float x) {
  union { float f; uint32_t u; } v; v.f = x;
  uint32_t u = v.u + 0x7FFFu + ((v.u >> 16) & 1u);   // RNE
  return (unsigned short)(u >> 16);
}
__device__ __forceinline__ float bf2f(unsigned short b) {
  return __uint_as_float(((uint32_t)b) << 16);
}
__device__ __forceinline__ int cellco(float v) {
  int c = (int)floorf((v - GORIG) * GINV);
  return c < 0 ? 0 : (c > GD - 1 ? GD - 1 : c);
}

// ---------------------------------------------------------------------------
// zero: count[GTOT] = 0  (must run before prep's atomics, every launch)
// ---------------------------------------------------------------------------
__global__ void zero_kernel(int* __restrict__ count) {
  int i = (blockIdx.x * 256 + threadIdx.x) * 4;
  *(int4*)(count + i) = make_int4(0, 0, 0, 0);
}

// ---------------------------------------------------------------------------
// prep: xb = bf16(x); pos4 = {x,y,z,pp}; ptcell[j] + count atomics; Wt.
// ---------------------------------------------------------------------------
__global__ void prep_kernel(const float* __restrict__ x,
                            const float* __restrict__ pos,
                            const float* __restrict__ W_att,
                            unsigned short* __restrict__ xb,
                            float4* __restrict__ pos4,
                            unsigned short* __restrict__ Wt,
                            int* __restrict__ ptcell,
                            int* __restrict__ count, int N) {
  int id = blockIdx.x * 256 + threadIdx.x;
  int nx8 = N * 8;
  if (id < nx8) {
    const float4* src = (const float4*)x + (size_t)id * 2;
    float4 a = src[0], b = src[1];
    short8 v;
    v[0] = (short)f2bf(a.x); v[1] = (short)f2bf(a.y);
    v[2] = (short)f2bf(a.z); v[3] = (short)f2bf(a.w);
    v[4] = (short)f2bf(b.x); v[5] = (short)f2bf(b.y);
    v[6] = (short)f2bf(b.z); v[7] = (short)f2bf(b.w);
    *(short8*)(xb + (size_t)id * 8) = v;
  } else if (id < nx8 + N) {
    int j = id - nx8;
    float px = pos[3 * j], py = pos[3 * j + 1], pz = pos[3 * j + 2];
    float pp = fmaf(px, px, fmaf(py, py, pz * pz));
    pos4[j] = make_float4(px, py, pz, pp);
    int cid = (cellco(pz) * GD + cellco(py)) * GD + cellco(px);
    ptcell[j] = cid;
    atomicAdd(&count[cid], 1);
  } else if (id < nx8 + N + 128 * 128) {
    int t = id - nx8 - N;
    int c = t >> 7, f = t & 127;
    Wt[f * 128 + c] = f2bf(W_att[t]);
  }
}

// ---------------------------------------------------------------------------
// two-level exclusive scan of count[GTOT] -> cell_start / cursor
// ---------------------------------------------------------------------------
__global__ __launch_bounds__(256) void scan1(const int* __restrict__ count,
                                             int* __restrict__ partial) {
  int b = blockIdx.x, t = threadIdx.x;
  int v = count[b * 256 + t];
#pragma unroll
  for (int off = 1; off < 64; off <<= 1) v += __shfl_xor(v, off);
  __shared__ int ws_[4];
  if ((t & 63) == 0) ws_[t >> 6] = v;
  __syncthreads();
  if (t == 0) partial[b] = ws_[0] + ws_[1] + ws_[2] + ws_[3];
}

__global__ __launch_bounds__(256) void scan2(int* __restrict__ partial,
                                             int* __restrict__ cell_start) {
  int t = threadIdx.x;
  int v0 = partial[t * 4], v1 = partial[t * 4 + 1];
  int v2 = partial[t * 4 + 2], v3 = partial[t * 4 + 3];
  int s1 = v0 + v1, s2 = s1 + v2, s3 = s2 + v3;
  int x = s3;
  int lane = t & 63, wv = t >> 6;
#pragma unroll
  for (int off = 1; off < 64; off <<= 1) {
    int y = __shfl_up(x, off);
    if (lane >= off) x += y;
  }
  __shared__ int wsum[4];
  if (lane == 63) wsum[wv] = x;
  __syncthreads();
  int base = 0;
  for (int k = 0; k < wv; ++k) base += wsum[k];
  int excl = base + x - s3;
  partial[t * 4]     = excl;
  partial[t * 4 + 1] = excl + v0;
  partial[t * 4 + 2] = excl + s1;
  partial[t * 4 + 3] = excl + s2;
  if (t == 255) cell_start[GTOT] = excl + s3;   // = N
}

__global__ __launch_bounds__(256) void scan3(const int* __restrict__ count,
                                             const int* __restrict__ partial,
                                             int* __restrict__ cell_start,
                                             int* __restrict__ cursor) {
  int b = blockIdx.x, t = threadIdx.x;
  int v = count[b * 256 + t];
  int x = v;
  int lane = t & 63, wv = t >> 6;
#pragma unroll
  for (int off = 1; off < 64; off <<= 1) {
    int y = __shfl_up(x, off);
    if (lane >= off) x += y;
  }
  __shared__ int wsum[4];
  if (lane == 63) wsum[wv] = x;
  __syncthreads();
  int base = partial[b];
  for (int k = 0; k < wv; ++k) base += wsum[k];
  int excl = base + x - v;
  cell_start[b * 256 + t] = excl;
  cursor[b * 256 + t] = excl;
}

// ---------------------------------------------------------------------------
// scatter: points into cell-sorted order (spos4 + original index sid)
// ---------------------------------------------------------------------------
__global__ void scatter_kernel(const float4* __restrict__ pos4,
                               const int* __restrict__ ptcell,
                               int* __restrict__ cursor,
                               float4* __restrict__ spos4,
                               int* __restrict__ sid, int N) {
  int j = blockIdx.x * 256 + threadIdx.x;
  if (j >= N) return;
  int cid = ptcell[j];
  int slot = atomicAdd(&cursor[cid], 1);
  spos4[slot] = pos4[j];
  sid[slot] = j;
}

// ---------------------------------------------------------------------------
// summed-volume table V (3D inclusive prefix of per-cell counts), 3 passes.
// ---------------------------------------------------------------------------
__global__ __launch_bounds__(256) void vscan_x(const int* __restrict__ count,
                                               int* __restrict__ V) {
  int row = blockIdx.x * 4 + (threadIdx.x >> 6);
  int ln = threadIdx.x & 63;
  int i = row * GD + ln;
  int v = count[i];
#pragma unroll
  for (int off = 1; off < 64; off <<= 1) {
    int y = __shfl_up(v, off);
    if (ln >= off) v += y;
  }
  V[i] = v;
}

__global__ __launch_bounds__(256) void vscan_y(int* __restrict__ V) {
  int pair = blockIdx.x * 4 + (threadIdx.x >> 6);   // z*64 + x
  int z = pair >> 6, x = pair & 63;
  int ln = threadIdx.x & 63;                        // y
  int i = (z * GD + ln) * GD + x;
  int v = V[i];
#pragma unroll
  for (int off = 1; off < 64; off <<= 1) {
    int y = __shfl_up(v, off);
    if (ln >= off) v += y;
  }
  V[i] = v;
}

__global__ __launch_bounds__(256) void vscan_z(int* __restrict__ V) {
  int pair = blockIdx.x * 4 + (threadIdx.x >> 6);   // y*64 + x
  int ln = threadIdx.x & 63;                        // z
  int i = ln * GD * GD + pair;
  int v = V[i];
#pragma unroll
  for (int off = 1; off < 64; off <<= 1) {
    int y = __shfl_up(v, off);
    if (ln >= off) v += y;
  }
  V[i] = v;
}

// ---------------------------------------------------------------------------
// top16_reg: exact top-16 of candw[0..tot) -> candw[0..16) (rank order);
// returns the 16th (largest) key. Candidates loaded ONCE into registers
// (R8-proven extraction), 16 extract-min rounds on registers.
// ---------------------------------------------------------------------------
__device__ __forceinline__ unsigned long long top16_reg(
    unsigned long long* candw, int tot, int ln) {
  unsigned long long c[CAPW / 64];
#pragma unroll
  for (int chk = 0; chk < CAPW / 64; ++chk) {
    int slot = chk * 64 + ln;
    c[chk] = (slot < tot) ? candw[slot] : ~0ull;
  }
  unsigned long long mykey = ~0ull, last = 0;
#pragma unroll
  for (int r = 0; r < KNB; ++r) {
    unsigned long long mn = c[0];
#pragma unroll
    for (int chk = 1; chk < CAPW / 64; ++chk) mn = (c[chk] < mn) ? c[chk] : mn;
#pragma unroll
    for (int off = 1; off < 64; off <<= 1) {
      unsigned long long o = __shfl_xor(mn, off);
      mn = (o < mn) ? o : mn;
    }
    if (ln == r) mykey = mn;
    last = mn;
#pragma unroll
    for (int chk = 0; chk < CAPW / 64; ++chk)
      if (c[chk] == mn) c[chk] = ~0ull;
  }
  if (ln < KNB) candw[ln] = mykey;
  return last;
}

// ---------------------------------------------------------------------------
// drain_annulus: drain all cells with Chebyshev radius in (slo, shi] around
// (cqx,cqy,cqz), clamped to grid. Rows with max(|dz|,|dy|) > slo are full
// x-rows; inner rows two x-segments excluding cube(slo). Flat cooperative
// drain (R8-proven). Compacts to exact top-16 (taukey) before overflow.
// ---------------------------------------------------------------------------
__device__ __forceinline__ void drain_annulus(
    const float4* __restrict__ spos4, const int* __restrict__ sid,
    const int* __restrict__ cell_start, unsigned long long* candw,
    uint32_t* rsAw, uint32_t* rlAw, uint32_t* rsBw, uint32_t* rpsw,
    float4 qp, int cqx, int cqy, int cqz, int slo, int shi, int ln,
    int& tot, unsigned long long& taukey) {
  const int z0 = (cqz - shi < 0) ? 0 : cqz - shi;
  const int z1 = (cqz + shi > GD - 1) ? GD - 1 : cqz + shi;
  const int y0 = (cqy - shi < 0) ? 0 : cqy - shi;
  const int y1 = (cqy + shi > GD - 1) ? GD - 1 : cqy + shi;
  const int wy = y1 - y0 + 1;
  const int npair = (z1 - z0 + 1) * wy;
  for (int base = 0; base < npair; base += 64) {
    int i = base + ln;
    int stA = 0, lA = 0, stB = 0, lB = 0;
    if (i < npair) {
      int zz = z0 + i / wy;
      int yy = y0 + (i - (i / wy) * wy);
      int dz = zz - cqz, dy = yy - cqy;
      int az = dz < 0 ? -dz : dz, ay = dy < 0 ? -dy : dy;
      int ch = az > ay ? az : ay;
      int rowbase = (zz * GD + yy) * GD;
      if (ch > slo) {
        int x0 = cqx - shi; if (x0 < 0) x0 = 0;
        int x1 = cqx + shi; if (x1 > GD - 1) x1 = GD - 1;
        stA = cell_start[rowbase + x0];
        lA  = cell_start[rowbase + x1 + 1] - stA;
      } else {
        int xl0 = cqx - shi; if (xl0 < 0) xl0 = 0;
        int xl1 = cqx - slo - 1;
        if (xl1 >= xl0) {
          stA = cell_start[rowbase + xl0];
          lA  = cell_start[rowbase + xl1 + 1] - stA;
        }
        int xr0 = cqx + slo + 1;
        int xr1 = cqx + shi; if (xr1 > GD - 1) xr1 = GD - 1;
        if (xr1 >= xr0) {
          stB = cell_start[rowbase + xr0];
          lB  = cell_start[rowbase + xr1 + 1] - stB;
        }
      }
    }
    int len = lA + lB;
    int xinc = len;
#pragma unroll
    for (int off = 1; off < 64; off <<= 1) {
      int y = __shfl_up(xinc, off);
      if (ln >= off) xinc += y;
    }
    int T = __shfl(xinc, 63);
    if (T == 0) continue;
    rpsw[ln] = (uint32_t)(xinc - len);   // exclusive prefix
    rsAw[ln] = (uint32_t)stA;
    rlAw[ln] = (uint32_t)lA;
    rsBw[ln] = (uint32_t)stB;
    for (int b2 = 0; b2 < T; b2 += 64) {
      if (tot + 64 > CAPW) {             // overflow-proof compaction (rare)
        taukey = top16_reg(candw, tot, ln);
        tot = KNB;
      }
      int flat = b2 + ln;
      unsigned long long key = ~0ull;
      bool ok = false;
      if (flat < T) {
        int lo = 0;
#pragma unroll
        for (int step = 32; step > 0; step >>= 1) {
          int mid = lo + step;
          if (mid <= 63 && (int)rpsw[mid] <= flat) lo = mid;
        }
        int o = flat - (int)rpsw[lo];
        uint32_t sa = rsAw[lo], la = rlAw[lo];
        int p = (o < (int)la) ? (int)(sa + o)
                              : (int)(rsBw[lo] + (uint32_t)(o - (int)la));
        float4 pj = spos4[p];
        float dot = fmaf(qp.x, pj.x, fmaf(qp.y, pj.y, qp.z * pj.z));
        float tt  = fmaf(-2.f, dot, pj.w);
        float d2  = fmaxf(qp.w + tt, 0.f);
        key = ((unsigned long long)__float_as_uint(d2) << 32) |
              (uint32_t)sid[p];
        ok = key < taukey;
      }
      unsigned long long bm = __ballot(ok);
      int pos = __popcll(bm & ((1ull << ln) - 1ull));
      if (ok) candw[tot + pos] = key;
      tot += __popcll(bm);
    }
  }
}

// ---------------------------------------------------------------------------
// knn_grid (R11): one wave per query, no shell walk (R10-proven structure).
// 1) lane-parallel probe via summed-volume table -> minimal s0 with
//    count(cube(s0)) >= PROBE_T.
// 2) round 1: drain cube(s0); register-based compact -> exact top-16, d16.
// 3) s1 = minimal s with r_expl(s)^2 >= d16^2; round 2: drain annulus
//    (s0, s1] with taukey filter (guarantee identical to proven
//    termination); final compact -> nbr.
// ---------------------------------------------------------------------------
__global__ __launch_bounds__(256) void knn_grid(
    const float4* __restrict__ pos4, const float4* __restrict__ spos4,
    const int* __restrict__ sid, const int* __restrict__ cell_start,
    const int* __restrict__ V, const int* __restrict__ idx,
    int* __restrict__ nbr, int M) {
  __shared__ unsigned long long cand[4][CAPW];
  __shared__ uint32_t rsA[4][64], rlA[4][64], rsB[4][64], rps[4][64];
  const int tid = threadIdx.x, wv = tid >> 6, ln = tid & 63;
  const int m = blockIdx.x * 4 + wv;
  if (m >= M) return;

  const float4 qp = pos4[idx[m]];
  const int cqx = cellco(qp.x), cqy = cellco(qp.y), cqz = cellco(qp.z);

  // --- lane-parallel minimal-cube probe via summed-volume table ---
  int s0;
  {
    int s = ln;
    int xh = cqx + s > GD - 1 ? GD - 1 : cqx + s;
    int yh = cqy + s > GD - 1 ? GD - 1 : cqy + s;
    int zh = cqz + s > GD - 1 ? GD - 1 : cqz + s;
    int xm = cqx - s - 1, ym = cqy - s - 1, zm = cqz - s - 1;
    int c = V[(zh * GD + yh) * GD + xh];
    if (zm >= 0) c -= V[(zm * GD + yh) * GD + xh];
    if (ym >= 0) c -= V[(zh * GD + ym) * GD + xh];
    if (xm >= 0) c -= V[(zh * GD + yh) * GD + xm];
    if (zm >= 0 && ym >= 0) c += V[(zm * GD + ym) * GD + xh];
    if (zm >= 0 && xm >= 0) c += V[(zm * GD + yh) * GD + xm];
    if (ym >= 0 && xm >= 0) c += V[(zh * GD + ym) * GD + xm];
    if (zm >= 0 && ym >= 0 && xm >= 0) c -= V[(zm * GD + ym) * GD + xm];
    unsigned long long bm = __ballot(c >= PROBE_T);
    s0 = __ffsll((unsigned long long)bm) - 1;   // bit 63 always set (c = N)
  }

  // --- round 1: drain cube(s0), compact to exact top-16 ---
  int tot = 0;
  unsigned long long taukey = ~0ull;
  drain_annulus(spos4, sid, cell_start, &cand[wv][0], &rsA[wv][0],
                &rlA[wv][0], &rsB[wv][0], &rps[wv][0], qp, cqx, cqy, cqz,
                -1, s0, ln, tot, taukey);
  taukey = top16_reg(&cand[wv][0], tot, ln);
  tot = KNB;
  float d16sq = __uint_as_float((uint32_t)(taukey >> 32));

  // --- s1: minimal radius whose guaranteed-explored ball covers d16 ---
  int s1 = s0;
  {
    float fx = qp.x - GORIG, fy = qp.y - GORIG, fz = qp.z - GORIG;
    while (s1 < GD - 1) {
      float r = 3.0e38f;
      if (cqx - s1 > 0)      r = fminf(r, fx - (float)(cqx - s1) * GEDGE);
      if (cqx + s1 < GD - 1) r = fminf(r, (float)(cqx + s1 + 1) * GEDGE - fx);
      if (cqy - s1 > 0)      r = fminf(r, fy - (float)(cqy - s1) * GEDGE);
      if (cqy + s1 < GD - 1) r = fminf(r, (float)(cqy + s1 + 1) * GEDGE - fy);
      if (cqz - s1 > 0)      r = fminf(r, fz - (float)(cqz - s1) * GEDGE);
      if (cqz + s1 < GD - 1) r = fminf(r, (float)(cqz + s1 + 1) * GEDGE - fz);
      float r2 = (r > 1.0e19f) ? 3.0e38f : r * r;
      if (r2 >= d16sq) break;
      ++s1;
    }
  }

  // --- round 2: drain annulus (s0, s1] with taukey filter ---
  if (s1 > s0) {
    drain_annulus(spos4, sid, cell_start, &cand[wv][0], &rsA[wv][0],
                  &rlA[wv][0], &rsB[wv][0], &rps[wv][0], qp, cqx, cqy, cqz,
                  s0, s1, ln, tot, taukey);
    if (tot > KNB) (void)top16_reg(&cand[wv][0], tot, ln);
  }

  if (ln < KNB) nbr[m * KNB + ln] = (int)(uint32_t)cand[wv][ln];
}

// ---------------------------------------------------------------------------
// mid: 8 queries / 256-thread block (unchanged from passing version).
// ---------------------------------------------------------------------------
__global__ __launch_bounds__(256) void mid_kernel(
    const unsigned short* __restrict__ xb, const float4* __restrict__ pos4,
    const int* __restrict__ idx, const float* __restrict__ W_pos,
    const float* __restrict__ b_pos, const unsigned short* __restrict__ Wt,
    const float* __restrict__ b_att, const int* __restrict__ nbr,
    float* __restrict__ aggr, int M) {
  __shared__ __align__(16) unsigned short fijb[8][16][136];
  __shared__ int nbr_s[128];
  __shared__ float4 qpos_s[8];

  const int tid = threadIdx.x;
  const int wid = tid >> 6, lane = tid & 63;
  const int col = lane & 15, quad = lane >> 4;
  const int b = blockIdx.x;

  if (tid < 128) {
    int mq = b * 8 + (tid >> 4); if (mq >= M) mq = M - 1;
    nbr_s[tid] = nbr[mq * 16 + (tid & 15)];
  }
  if (tid < 8) {
    int mq = b * 8 + tid; if (mq >= M) mq = M - 1;
    qpos_s[tid] = pos4[idx[mq]];
  }
  float wp[10];
#pragma unroll
  for (int t = 0; t < 10; ++t) wp[t] = W_pos[t * 64 + lane];
  float bp = b_pos[lane];
  __syncthreads();

  {
    int rr = tid >> 1, h = tid & 1;
    int jn = nbr_s[rr];
    const short8* src = (const short8*)(xb + ((size_t)jn << 6) + (h << 5));
    short8 v0 = src[0], v1 = src[1], v2 = src[2], v3 = src[3];
    short8* dst = (short8*)&fijb[rr >> 4][rr & 15][h * 32];
    dst[0] = v0; dst[1] = v1; dst[2] = v2; dst[3] = v3;
  }
#pragma unroll
  for (int qi = 0; qi < 2; ++qi) {
    int q = wid * 2 + qi;
    float4 qp = qpos_s[q];
#pragma unroll 4
    for (int k = 0; k < 16; ++k) {
      int jn = nbr_s[q * 16 + k];
      float4 pj = pos4[jn];
      float vx = qp.x - pj.x, vy = qp.y - pj.y, vz = qp.z - pj.z;
      float dd = sqrtf(fmaf(vx, vx, fmaf(vy, vy, vz * vz)));
      float r = bp;
      r = fmaf(qp.x, wp[0], r); r = fmaf(qp.y, wp[1], r); r = fmaf(qp.z, wp[2], r);
      r = fmaf(pj.x, wp[3], r); r = fmaf(pj.y, wp[4], r); r = fmaf(pj.z, wp[5], r);
      r = fmaf(vx, wp[6], r);  r = fmaf(vy, wp[7], r);  r = fmaf(vz, wp[8], r);
      r = fmaf(dd, wp[9], r);
      r = fmaxf(r, 0.f);
      fijb[q][k][64 + lane] = f2bf(r);
    }
  }
  __syncthreads();

#pragma unroll 1
  for (int qi = 0; qi < 2; ++qi) {
    int q = wid * 2 + qi;
    int mq = b * 8 + q;

    short8 af[4];
#pragma unroll
    for (int cs = 0; cs < 4; ++cs)
      af[cs] = *(const short8*)&fijb[q][col][cs * 32 + quad * 8];

    floatx4 acc[8];
#pragma unroll
    for (int ft = 0; ft < 8; ++ft) {
      float bav = b_att[ft * 16 + col];
      floatx4 a = {bav, bav, bav, bav};
#pragma unroll
      for (int cs = 0; cs < 4; ++cs) {
        short8 bfrag =
            *(const short8*)&Wt[(ft * 16 + col) * 128 + cs * 32 + quad * 8];
        a = __builtin_amdgcn_mfma_f32_16x16x32_bf16(af[cs], bfrag, a, 0, 0, 0);
      }
      acc[ft] = a;
    }

    float rowmax[4], rowinv[4];
#pragma unroll
    for (int r = 0; r < 4; ++r) {
      float mx = acc[0][r];
#pragma unroll
      for (int ft = 1; ft < 8; ++ft) mx = fmaxf(mx, acc[ft][r]);
      mx = fmaxf(mx, __shfl_xor(mx, 1));
      mx = fmaxf(mx, __shfl_xor(mx, 2));
      mx = fmaxf(mx, __shfl_xor(mx, 4));
      mx = fmaxf(mx, __shfl_xor(mx, 8));
      float sm = 0.f;
#pragma unroll
      for (int ft = 0; ft < 8; ++ft) sm += __expf(acc[ft][r] - mx);
      sm += __shfl_xor(sm, 1);
      sm += __shfl_xor(sm, 2);
      sm += __shfl_xor(sm, 4);
      sm += __shfl_xor(sm, 8);
      rowmax[r] = mx;
      rowinv[r] = 1.0f / sm;
    }

#pragma unroll
    for (int ft = 0; ft < 8; ++ft) {
      float ap = 0.f;
#pragma unroll
      for (int r = 0; r < 4; ++r) {
        float s = __expf(acc[ft][r] - rowmax[r]) * rowinv[r];
        float fv = bf2f(fijb[q][quad * 4 + r][ft * 16 + col]);
        ap = fmaf(s, fv, ap);
      }
      ap += __shfl_xor(ap, 16);
      ap += __shfl_xor(ap, 32);
      if (quad == 0 && mq < M)
        aggr[mq * 128 + ft * 16 + col] = ap * (1.0f / 16.0f);
    }
  }
}

// ---------------------------------------------------------------------------
// out = relu(aggr @ W_glob + b_glob)
// ---------------------------------------------------------------------------
__global__ __launch_bounds__(256) void out_kernel(
    const float* __restrict__ aggr, const float* __restrict__ W_glob,
    const float* __restrict__ b_glob, float* __restrict__ out, int M) {
  __shared__ float ag[16][128];
  const int tid = threadIdx.x;
  const int mbase = blockIdx.x * 16;
  for (int s = tid; s < 16 * 128; s += 256) {
    int r = s >> 7, cc = s & 127;
    int m = mbase + r;
    ((float*)ag)[s] = (m < M) ? aggr[m * 128 + cc] : 0.0f;
  }
  __syncthreads();
  const int f = tid & 127, h = tid >> 7;
  float acc[8];
  float bg = b_glob[f];
#pragma unroll
  for (int i = 0; i < 8; ++i) acc[i] = bg;
  for (int c = 0; c < 128; c += 4) {
    float w0 = W_glob[(c + 0) * 128 + f];
    float w1 = W_glob[(c + 1) * 128 + f];
    float w2 = W_glob[(c + 2) * 128 + f];
    float w3 = W_glob[(c + 3) * 128 + f];
#pragma unroll
    for (int i = 0; i < 8; ++i) {
      const floatx4 a4 = *(const floatx4*)&ag[h * 8 + i][c];
      acc[i] += a4[0] * w0 + a4[1] * w1 + a4[2] * w2 + a4[3] * w3;
    }
  }
#pragma unroll
  for (int i = 0; i < 8; ++i) {
    int m = mbase + h * 8 + i;
    if (m < M) out[m * 128 + f] = fmaxf(acc[i], 0.0f);
  }
}

// ---------------------------------------------------------------------------
extern "C" void kernel_launch(void* const* d_in, const int* in_sizes, int n_in,
                              void* d_out, int out_size, void* d_ws,
                              size_t ws_size, hipStream_t stream) {
  const float* x      = (const float*)d_in[0];
  const float* pos    = (const float*)d_in[1];
  const int*   idx    = (const int*)d_in[2];
  const float* W_pos  = (const float*)d_in[3];
  const float* b_pos  = (const float*)d_in[4];
  const float* W_att  = (const float*)d_in[5];
  const float* b_att  = (const float*)d_in[6];
  const float* W_glob = (const float*)d_in[7];
  const float* b_glob = (const float*)d_in[8];
  float* out = (float*)d_out;

  const int N = in_sizes[1] / 3;
  const int M = in_sizes[2];

  char* ws = (char*)d_ws;
  size_t o = 0;
  float4* pos4 = (float4*)(ws + o);               o += ((size_t)N * 16 + 255) & ~(size_t)255;
  unsigned short* xb = (unsigned short*)(ws + o); o += ((size_t)N * 128 + 255) & ~(size_t)255;
  unsigned short* Wt = (unsigned short*)(ws + o); o += (128 * 128 * 2 + 255) & ~(size_t)255;
  int* nbr = (int*)(ws + o);                      o += (((size_t)M * KNB * 4) + 255) & ~(size_t)255;
  int* ptcell = (int*)(ws + o);                   o += (((size_t)N * 4) + 255) & ~(size_t)255;
  int* count = (int*)(ws + o);                    o += ((size_t)GTOT * 4 + 255) & ~(size_t)255;
  int* cursor = (int*)(ws + o);                   o += ((size_t)GTOT * 4 + 255) & ~(size_t)255;
  int* cell_start = (int*)(ws + o);               o += ((size_t)(GTOT + 1) * 4 + 255) & ~(size_t)255;
  int* V = (int*)(ws + o);                        o += ((size_t)GTOT * 4 + 255) & ~(size_t)255;
  int* partial = (int*)(ws + o);                  o += (1024 * 4 + 255) & ~(size_t)255;
  float4* spos4 = (float4*)(ws + o);              o += ((size_t)N * 16 + 255) & ~(size_t)255;
  int* sid = (int*)(ws + o);                      o += (((size_t)N * 4) + 255) & ~(size_t)255;
  float* aggr = (float*)(ws + o);                 o += ((size_t)M * 128 * 4 + 255) & ~(size_t)255;

  zero_kernel<<<GTOT / 1024, 256, 0, stream>>>(count);

  int prep_ids = N * 8 + N + 128 * 128;
  prep_kernel<<<(prep_ids + 255) / 256, 256, 0, stream>>>(
      x, pos, W_att, xb, pos4, Wt, ptcell, count, N);

  scan1<<<GTOT / 256, 256, 0, stream>>>(count, partial);
  scan2<<<1, 256, 0, stream>>>(partial, cell_start);
  scan3<<<GTOT / 256, 256, 0, stream>>>(count, partial, cell_start, cursor);

  scatter_kernel<<<(N + 255) / 256, 256, 0, stream>>>(pos4, ptcell, cursor,
                                                      spos4, sid, N);

  vscan_x<<<1024, 256, 0, stream>>>(count, V);
  vscan_y<<<1024, 256, 0, stream>>>(V);
  vscan_z<<<1024, 256, 0, stream>>>(V);

  knn_grid<<<(M + 3) / 4, 256, 0, stream>>>(pos4, spos4, sid, cell_start, V,
                                            idx, nbr, M);

  mid_kernel<<<(M + 7) / 8, 256, 0, stream>>>(xb, pos4, idx, W_pos, b_pos, Wt,
                                              b_att, nbr, aggr, M);
  out_kernel<<<(M + 15) / 16, 256, 0, stream>>>(aggr, W_glob, b_glob, out, M);
}

// Round 14
// 203.752 us; speedup vs baseline: 1.3092x; 1.0221x over previous
//
#include <hip/hip_runtime.h>
#include <stdint.h>

#define KNB     16
#define GD      64                  // grid cells per axis
#define GTOT    (GD * GD * GD)      // 262144 cells
#define GORIG   (-6.5f)
#define GEDGE   0.203125f           // 13.0 / 64
#define GINV    (1.0f / GEDGE)
#define CAPW    640                 // per-query candidate capacity (10 x 64)
#define PROBE_T 48                  // min cube count for round-1 (>= KNB)

typedef short short8 __attribute__((ext_vector_type(8)));
typedef float floatx4 __attribute__((ext_vector_type(4)));

__device__ __forceinline__ unsigned short f2bf(float x) {
  union { float f; uint32_t u; } v; v.f = x;
  uint32_t u = v.u + 0x7FFFu + ((v.u >> 16) & 1u);   // RNE
  return (unsigned short)(u >> 16);
}
__device__ __forceinline__ float bf2f(unsigned short b) {
  return __uint_as_float(((uint32_t)b) << 16);
}
__device__ __forceinline__ int cellco(float v) {
  int c = (int)floorf((v - GORIG) * GINV);
  return c < 0 ? 0 : (c > GD - 1 ? GD - 1 : c);
}

// ---------------------------------------------------------------------------
// zero: count[GTOT] = 0  (must run before prep's atomics, every launch)
// ---------------------------------------------------------------------------
__global__ void zero_kernel(int* __restrict__ count) {
  int i = (blockIdx.x * 256 + threadIdx.x) * 4;
  *(int4*)(count + i) = make_int4(0, 0, 0, 0);
}

// ---------------------------------------------------------------------------
// prep: xb = bf16(x); pos4 = {x,y,z,pp}; ptcell[j] + count atomics; Wt.
// ---------------------------------------------------------------------------
__global__ void prep_kernel(const float* __restrict__ x,
                            const float* __restrict__ pos,
                            const float* __restrict__ W_att,
                            unsigned short* __restrict__ xb,
                            float4* __restrict__ pos4,
                            unsigned short* __restrict__ Wt,
                            int* __restrict__ ptcell,
                            int* __restrict__ count, int N) {
  int id = blockIdx.x * 256 + threadIdx.x;
  int nx8 = N * 8;
  if (id < nx8) {
    const float4* src = (const float4*)x + (size_t)id * 2;
    float4 a = src[0], b = src[1];
    short8 v;
    v[0] = (short)f2bf(a.x); v[1] = (short)f2bf(a.y);
    v[2] = (short)f2bf(a.z); v[3] = (short)f2bf(a.w);
    v[4] = (short)f2bf(b.x); v[5] = (short)f2bf(b.y);
    v[6] = (short)f2bf(b.z); v[7] = (short)f2bf(b.w);
    *(short8*)(xb + (size_t)id * 8) = v;
  } else if (id < nx8 + N) {
    int j = id - nx8;
    float px = pos[3 * j], py = pos[3 * j + 1], pz = pos[3 * j + 2];
    float pp = fmaf(px, px, fmaf(py, py, pz * pz));
    pos4[j] = make_float4(px, py, pz, pp);
    int cid = (cellco(pz) * GD + cellco(py)) * GD + cellco(px);
    ptcell[j] = cid;
    atomicAdd(&count[cid], 1);
  } else if (id < nx8 + N + 128 * 128) {
    int t = id - nx8 - N;
    int c = t >> 7, f = t & 127;
    Wt[f * 128 + c] = f2bf(W_att[t]);
  }
}

// ---------------------------------------------------------------------------
// summed-volume table V (3D inclusive prefix of per-cell counts), 3 passes.
// ---------------------------------------------------------------------------
__global__ __launch_bounds__(256) void vscan_x(const int* __restrict__ count,
                                               int* __restrict__ V) {
  int row = blockIdx.x * 4 + (threadIdx.x >> 6);
  int ln = threadIdx.x & 63;
  int i = row * GD + ln;
  int v = count[i];
#pragma unroll
  for (int off = 1; off < 64; off <<= 1) {
    int y = __shfl_up(v, off);
    if (ln >= off) v += y;
  }
  V[i] = v;
}

__global__ __launch_bounds__(256) void vscan_y(int* __restrict__ V) {
  int pair = blockIdx.x * 4 + (threadIdx.x >> 6);   // z*64 + x
  int z = pair >> 6, x = pair & 63;
  int ln = threadIdx.x & 63;                        // y
  int i = (z * GD + ln) * GD + x;
  int v = V[i];
#pragma unroll
  for (int off = 1; off < 64; off <<= 1) {
    int y = __shfl_up(v, off);
    if (ln >= off) v += y;
  }
  V[i] = v;
}

__global__ __launch_bounds__(256) void vscan_z(int* __restrict__ V) {
  int pair = blockIdx.x * 4 + (threadIdx.x >> 6);   // y*64 + x
  int ln = threadIdx.x & 63;                        // z
  int i = ln * GD * GD + pair;
  int v = V[i];
#pragma unroll
  for (int off = 1; off < 64; off <<= 1) {
    int y = __shfl_up(v, off);
    if (ln >= off) v += y;
  }
  V[i] = v;
}

// ---------------------------------------------------------------------------
// derive: cell_start (exclusive z-major prefix of per-cell counts) + cursor
// from the inclusive summed-volume table V:
//   start(z,y,x) = slabs(z' < z) + rows(y' < y in slab z) + partial row
// (replaces the 3-kernel scan chain; thread 0 writes cell_start[GTOT] = N)
// ---------------------------------------------------------------------------
__global__ __launch_bounds__(256) void derive_kernel(
    const int* __restrict__ V, int* __restrict__ cell_start,
    int* __restrict__ cursor) {
  int cid = blockIdx.x * 256 + threadIdx.x;
  int x = cid & 63, y = (cid >> 6) & 63, z = cid >> 12;
  int s = 0;
  if (z > 0) s += V[((z - 1) * GD + 63) * GD + 63];
  if (y > 0) {
    s += V[(z * GD + (y - 1)) * GD + 63];
    if (z > 0) s -= V[((z - 1) * GD + (y - 1)) * GD + 63];
  }
  if (x > 0) {
    s += V[(z * GD + y) * GD + (x - 1)];
    if (y > 0) s -= V[(z * GD + (y - 1)) * GD + (x - 1)];
    if (z > 0) s -= V[((z - 1) * GD + y) * GD + (x - 1)];
    if (z > 0 && y > 0) s += V[((z - 1) * GD + (y - 1)) * GD + (x - 1)];
  }
  cell_start[cid] = s;
  cursor[cid] = s;
  if (cid == 0) cell_start[GTOT] = V[GTOT - 1];   // = N
}

// ---------------------------------------------------------------------------
// scatter: points into cell-sorted order (spos4 + original index sid)
// ---------------------------------------------------------------------------
__global__ void scatter_kernel(const float4* __restrict__ pos4,
                               const int* __restrict__ ptcell,
                               int* __restrict__ cursor,
                               float4* __restrict__ spos4,
                               int* __restrict__ sid, int N) {
  int j = blockIdx.x * 256 + threadIdx.x;
  if (j >= N) return;
  int cid = ptcell[j];
  int slot = atomicAdd(&cursor[cid], 1);
  spos4[slot] = pos4[j];
  sid[slot] = j;
}

// ---------------------------------------------------------------------------
// top16_reg: exact top-16 of candw[0..tot) -> candw[0..16) (rank order);
// returns the 16th (largest) key. Candidates loaded ONCE into registers
// (R8-proven extraction), 16 extract-min rounds on registers.
// Called only with the whole wave active.
// ---------------------------------------------------------------------------
__device__ __forceinline__ unsigned long long top16_reg(
    unsigned long long* candw, int tot, int ln) {
  unsigned long long c[CAPW / 64];
#pragma unroll
  for (int chk = 0; chk < CAPW / 64; ++chk) {
    int slot = chk * 64 + ln;
    c[chk] = (slot < tot) ? candw[slot] : ~0ull;
  }
  unsigned long long mykey = ~0ull, last = 0;
#pragma unroll
  for (int r = 0; r < KNB; ++r) {
    unsigned long long mn = c[0];
#pragma unroll
    for (int chk = 1; chk < CAPW / 64; ++chk) mn = (c[chk] < mn) ? c[chk] : mn;
#pragma unroll
    for (int off = 1; off < 64; off <<= 1) {
      unsigned long long o = __shfl_xor(mn, off);
      mn = (o < mn) ? o : mn;
    }
    if (ln == r) mykey = mn;
    last = mn;
#pragma unroll
    for (int chk = 0; chk < CAPW / 64; ++chk)
      if (c[chk] == mn) c[chk] = ~0ull;
  }
  if (ln < KNB) candw[ln] = mykey;
  return last;
}

// ---------------------------------------------------------------------------
// drain_annulus: drain all cells with Chebyshev radius in (slo, shi] around
// (cqx,cqy,cqz), clamped to grid. Rows with max(|dz|,|dy|) > slo are full
// x-rows; inner rows two x-segments excluding cube(slo). Flat cooperative
// drain; row tables in REGISTERS, flat-index -> row mapping via 6-step
// __shfl binary search over the wave-held exclusive prefix.
// FIX (R14): the shfl search runs with ALL 64 LANES ACTIVE — `flat` is
// clamped to T-1 for tail lanes instead of branching around the search.
// On CDNA, __shfl (ds_bpermute) from an INACTIVE lane is undefined; the
// R12/R13 divergent version read garbage row tables in the last partial
// chunk (R12: OOB fault; R13: wrong neighbors). Validity is folded into
// `ok` which only gates the ballot/store. Compacts to exact top-16
// (taukey) before any chunk could overflow CAPW.
// ---------------------------------------------------------------------------
__device__ __forceinline__ void drain_annulus(
    const float4* __restrict__ spos4, const int* __restrict__ sid,
    const int* __restrict__ cell_start, unsigned long long* candw,
    float4 qp, int cqx, int cqy, int cqz, int slo, int shi, int ln,
    int& tot, unsigned long long& taukey) {
  const int z0 = (cqz - shi < 0) ? 0 : cqz - shi;
  const int z1 = (cqz + shi > GD - 1) ? GD - 1 : cqz + shi;
  const int y0 = (cqy - shi < 0) ? 0 : cqy - shi;
  const int y1 = (cqy + shi > GD - 1) ? GD - 1 : cqy + shi;
  const int wy = y1 - y0 + 1;
  const int npair = (z1 - z0 + 1) * wy;
  for (int base = 0; base < npair; base += 64) {
    int i = base + ln;
    int stA = 0, lA = 0, stB = 0, lB = 0;
    if (i < npair) {
      int zz = z0 + i / wy;
      int yy = y0 + (i - (i / wy) * wy);
      int dz = zz - cqz, dy = yy - cqy;
      int az = dz < 0 ? -dz : dz, ay = dy < 0 ? -dy : dy;
      int ch = az > ay ? az : ay;
      int rowbase = (zz * GD + yy) * GD;
      if (ch > slo) {
        int x0 = cqx - shi; if (x0 < 0) x0 = 0;
        int x1 = cqx + shi; if (x1 > GD - 1) x1 = GD - 1;
        stA = cell_start[rowbase + x0];
        lA  = cell_start[rowbase + x1 + 1] - stA;
      } else {
        int xl0 = cqx - shi; if (xl0 < 0) xl0 = 0;
        int xl1 = cqx - slo - 1;
        if (xl1 >= xl0) {
          stA = cell_start[rowbase + xl0];
          lA  = cell_start[rowbase + xl1 + 1] - stA;
        }
        int xr0 = cqx + slo + 1;
        int xr1 = cqx + shi; if (xr1 > GD - 1) xr1 = GD - 1;
        if (xr1 >= xr0) {
          stB = cell_start[rowbase + xr0];
          lB  = cell_start[rowbase + xr1 + 1] - stB;
        }
      }
    }
    int len = lA + lB;
    int xinc = len;
#pragma unroll
    for (int off = 1; off < 64; off <<= 1) {
      int y = __shfl_up(xinc, off);
      if (ln >= off) xinc += y;
    }
    int T = __shfl(xinc, 63);
    if (T == 0) continue;
    int ps_ex = xinc - len;            // exclusive prefix (register, per-lane)

    for (int b2 = 0; b2 < T; b2 += 64) {
      if (tot + 64 > CAPW) {           // overflow-proof compaction (rare)
        taukey = top16_reg(candw, tot, ln);
        tot = KNB;
      }
      int flat = b2 + ln;
      bool valid = flat < T;
      int flatc = valid ? flat : (T - 1);   // clamp: all lanes stay active
      // shfl binary search (all lanes): largest l with ps[l] <= flatc
      int lo = 0;
#pragma unroll
      for (int step = 32; step > 0; step >>= 1) {
        int mid = lo + step;
        int v = __shfl(ps_ex, mid & 63);
        if (mid <= 63 && v <= flatc) lo = mid;
      }
      int psl = __shfl(ps_ex, lo);
      int sa  = __shfl(stA, lo);
      int la  = __shfl(lA, lo);
      int sb  = __shfl(stB, lo);
      int o = flatc - psl;
      int p = (o < la) ? (sa + o) : (sb + (o - la));
      float4 pj = spos4[p];
      float dot = fmaf(qp.x, pj.x, fmaf(qp.y, pj.y, qp.z * pj.z));
      float tt  = fmaf(-2.f, dot, pj.w);
      float d2  = fmaxf(qp.w + tt, 0.f);
      unsigned long long key =
          ((unsigned long long)__float_as_uint(d2) << 32) | (uint32_t)sid[p];
      bool ok = valid && (key < taukey);
      unsigned long long bm = __ballot(ok);
      int pos = __popcll(bm & ((1ull << ln) - 1ull));
      if (ok) candw[tot + pos] = key;
      tot += __popcll(bm);
    }
  }
}

// ---------------------------------------------------------------------------
// knn_grid (R14): one wave per query, no shell walk (R10/R11-proven).
// 1) lane-parallel probe via summed-volume table -> minimal s0 with
//    count(cube(s0)) >= PROBE_T.
// 2) round 1: drain cube(s0); register-based compact -> exact top-16, d16.
// 3) s1 = minimal s with r_expl(s)^2 >= d16^2; round 2: drain annulus
//    (s0, s1] with taukey filter (guarantee identical to proven
//    termination); final compact -> nbr.
// ---------------------------------------------------------------------------
__global__ __launch_bounds__(256) void knn_grid(
    const float4* __restrict__ pos4, const float4* __restrict__ spos4,
    const int* __restrict__ sid, const int* __restrict__ cell_start,
    const int* __restrict__ V, const int* __restrict__ idx,
    int* __restrict__ nbr, int M) {
  __shared__ unsigned long long cand[4][CAPW];
  const int tid = threadIdx.x, wv = tid >> 6, ln = tid & 63;
  const int m = blockIdx.x * 4 + wv;
  if (m >= M) return;   // whole-wave exit (m uniform per wave)

  const float4 qp = pos4[idx[m]];
  const int cqx = cellco(qp.x), cqy = cellco(qp.y), cqz = cellco(qp.z);

  // --- lane-parallel minimal-cube probe via summed-volume table ---
  int s0;
  {
    int s = ln;
    int xh = cqx + s > GD - 1 ? GD - 1 : cqx + s;
    int yh = cqy + s > GD - 1 ? GD - 1 : cqy + s;
    int zh = cqz + s > GD - 1 ? GD - 1 : cqz + s;
    int xm = cqx - s - 1, ym = cqy - s - 1, zm = cqz - s - 1;
    int c = V[(zh * GD + yh) * GD + xh];
    if (zm >= 0) c -= V[(zm * GD + yh) * GD + xh];
    if (ym >= 0) c -= V[(zh * GD + ym) * GD + xh];
    if (xm >= 0) c -= V[(zh * GD + yh) * GD + xm];
    if (zm >= 0 && ym >= 0) c += V[(zm * GD + ym) * GD + xh];
    if (zm >= 0 && xm >= 0) c += V[(zm * GD + yh) * GD + xm];
    if (ym >= 0 && xm >= 0) c += V[(zh * GD + ym) * GD + xm];
    if (zm >= 0 && ym >= 0 && xm >= 0) c -= V[(zm * GD + ym) * GD + xm];
    unsigned long long bm = __ballot(c >= PROBE_T);
    s0 = __ffsll((unsigned long long)bm) - 1;   // bit 63 always set (c = N)
  }

  // --- round 1: drain cube(s0), compact to exact top-16 ---
  int tot = 0;
  unsigned long long taukey = ~0ull;
  drain_annulus(spos4, sid, cell_start, &cand[wv][0], qp, cqx, cqy, cqz,
                -1, s0, ln, tot, taukey);
  taukey = top16_reg(&cand[wv][0], tot, ln);
  tot = KNB;
  float d16sq = __uint_as_float((uint32_t)(taukey >> 32));

  // --- s1: minimal radius whose guaranteed-explored ball covers d16 ---
  int s1 = s0;
  {
    float fx = qp.x - GORIG, fy = qp.y - GORIG, fz = qp.z - GORIG;
    while (s1 < GD - 1) {
      float r = 3.0e38f;
      if (cqx - s1 > 0)      r = fminf(r, fx - (float)(cqx - s1) * GEDGE);
      if (cqx + s1 < GD - 1) r = fminf(r, (float)(cqx + s1 + 1) * GEDGE - fx);
      if (cqy - s1 > 0)      r = fminf(r, fy - (float)(cqy - s1) * GEDGE);
      if (cqy + s1 < GD - 1) r = fminf(r, (float)(cqy + s1 + 1) * GEDGE - fy);
      if (cqz - s1 > 0)      r = fminf(r, fz - (float)(cqz - s1) * GEDGE);
      if (cqz + s1 < GD - 1) r = fminf(r, (float)(cqz + s1 + 1) * GEDGE - fz);
      float r2 = (r > 1.0e19f) ? 3.0e38f : r * r;
      if (r2 >= d16sq) break;
      ++s1;
    }
  }

  // --- round 2: drain annulus (s0, s1] with taukey filter ---
  if (s1 > s0) {
    drain_annulus(spos4, sid, cell_start, &cand[wv][0], qp, cqx, cqy, cqz,
                  s0, s1, ln, tot, taukey);
    if (tot > KNB) (void)top16_reg(&cand[wv][0], tot, ln);
  }

  if (ln < KNB) nbr[m * KNB + ln] = (int)(uint32_t)cand[wv][ln];
}

// ---------------------------------------------------------------------------
// mid: 8 queries / 256-thread block (unchanged from passing version).
// ---------------------------------------------------------------------------
__global__ __launch_bounds__(256) void mid_kernel(
    const unsigned short* __restrict__ xb, const float4* __restrict__ pos4,
    const int* __restrict__ idx, const float* __restrict__ W_pos,
    const float* __restrict__ b_pos, const unsigned short* __restrict__ Wt,
    const float* __restrict__ b_att, const int* __restrict__ nbr,
    float* __restrict__ aggr, int M) {
  __shared__ __align__(16) unsigned short fijb[8][16][136];
  __shared__ int nbr_s[128];
  __shared__ float4 qpos_s[8];

  const int tid = threadIdx.x;
  const int wid = tid >> 6, lane = tid & 63;
  const int col = lane & 15, quad = lane >> 4;
  const int b = blockIdx.x;

  if (tid < 128) {
    int mq = b * 8 + (tid >> 4); if (mq >= M) mq = M - 1;
    nbr_s[tid] = nbr[mq * 16 + (tid & 15)];
  }
  if (tid < 8) {
    int mq = b * 8 + tid; if (mq >= M) mq = M - 1;
    qpos_s[tid] = pos4[idx[mq]];
  }
  float wp[10];
#pragma unroll
  for (int t = 0; t < 10; ++t) wp[t] = W_pos[t * 64 + lane];
  float bp = b_pos[lane];
  __syncthreads();

  {
    int rr = tid >> 1, h = tid & 1;
    int jn = nbr_s[rr];
    const short8* src = (const short8*)(xb + ((size_t)jn << 6) + (h << 5));
    short8 v0 = src[0], v1 = src[1], v2 = src[2], v3 = src[3];
    short8* dst = (short8*)&fijb[rr >> 4][rr & 15][h * 32];
    dst[0] = v0; dst[1] = v1; dst[2] = v2; dst[3] = v3;
  }
#pragma unroll
  for (int qi = 0; qi < 2; ++qi) {
    int q = wid * 2 + qi;
    float4 qp = qpos_s[q];
#pragma unroll 4
    for (int k = 0; k < 16; ++k) {
      int jn = nbr_s[q * 16 + k];
      float4 pj = pos4[jn];
      float vx = qp.x - pj.x, vy = qp.y - pj.y, vz = qp.z - pj.z;
      float dd = sqrtf(fmaf(vx, vx, fmaf(vy, vy, vz * vz)));
      float r = bp;
      r = fmaf(qp.x, wp[0], r); r = fmaf(qp.y, wp[1], r); r = fmaf(qp.z, wp[2], r);
      r = fmaf(pj.x, wp[3], r); r = fmaf(pj.y, wp[4], r); r = fmaf(pj.z, wp[5], r);
      r = fmaf(vx, wp[6], r);  r = fmaf(vy, wp[7], r);  r = fmaf(vz, wp[8], r);
      r = fmaf(dd, wp[9], r);
      r = fmaxf(r, 0.f);
      fijb[q][k][64 + lane] = f2bf(r);
    }
  }
  __syncthreads();

#pragma unroll 1
  for (int qi = 0; qi < 2; ++qi) {
    int q = wid * 2 + qi;
    int mq = b * 8 + q;

    short8 af[4];
#pragma unroll
    for (int cs = 0; cs < 4; ++cs)
      af[cs] = *(const short8*)&fijb[q][col][cs * 32 + quad * 8];

    floatx4 acc[8];
#pragma unroll
    for (int ft = 0; ft < 8; ++ft) {
      float bav = b_att[ft * 16 + col];
      floatx4 a = {bav, bav, bav, bav};
#pragma unroll
      for (int cs = 0; cs < 4; ++cs) {
        short8 bfrag =
            *(const short8*)&Wt[(ft * 16 + col) * 128 + cs * 32 + quad * 8];
        a = __builtin_amdgcn_mfma_f32_16x16x32_bf16(af[cs], bfrag, a, 0, 0, 0);
      }
      acc[ft] = a;
    }

    float rowmax[4], rowinv[4];
#pragma unroll
    for (int r = 0; r < 4; ++r) {
      float mx = acc[0][r];
#pragma unroll
      for (int ft = 1; ft < 8; ++ft) mx = fmaxf(mx, acc[ft][r]);
      mx = fmaxf(mx, __shfl_xor(mx, 1));
      mx = fmaxf(mx, __shfl_xor(mx, 2));
      mx = fmaxf(mx, __shfl_xor(mx, 4));
      mx = fmaxf(mx, __shfl_xor(mx, 8));
      float sm = 0.f;
#pragma unroll
      for (int ft = 0; ft < 8; ++ft) sm += __expf(acc[ft][r] - mx);
      sm += __shfl_xor(sm, 1);
      sm += __shfl_xor(sm, 2);
      sm += __shfl_xor(sm, 4);
      sm += __shfl_xor(sm, 8);
      rowmax[r] = mx;
      rowinv[r] = 1.0f / sm;
    }

#pragma unroll
    for (int ft = 0; ft < 8; ++ft) {
      float ap = 0.f;
#pragma unroll
      for (int r = 0; r < 4; ++r) {
        float s = __expf(acc[ft][r] - rowmax[r]) * rowinv[r];
        float fv = bf2f(fijb[q][quad * 4 + r][ft * 16 + col]);
        ap = fmaf(s, fv, ap);
      }
      ap += __shfl_xor(ap, 16);
      ap += __shfl_xor(ap, 32);
      if (quad == 0 && mq < M)
        aggr[mq * 128 + ft * 16 + col] = ap * (1.0f / 16.0f);
    }
  }
}

// ---------------------------------------------------------------------------
// out = relu(aggr @ W_glob + b_glob)
// ---------------------------------------------------------------------------
__global__ __launch_bounds__(256) void out_kernel(
    const float* __restrict__ aggr, const float* __restrict__ W_glob,
    const float* __restrict__ b_glob, float* __restrict__ out, int M) {
  __shared__ float ag[16][128];
  const int tid = threadIdx.x;
  const int mbase = blockIdx.x * 16;
  for (int s = tid; s < 16 * 128; s += 256) {
    int r = s >> 7, cc = s & 127;
    int m = mbase + r;
    ((float*)ag)[s] = (m < M) ? aggr[m * 128 + cc] : 0.0f;
  }
  __syncthreads();
  const int f = tid & 127, h = tid >> 7;
  float acc[8];
  float bg = b_glob[f];
#pragma unroll
  for (int i = 0; i < 8; ++i) acc[i] = bg;
  for (int c = 0; c < 128; c += 4) {
    float w0 = W_glob[(c + 0) * 128 + f];
    float w1 = W_glob[(c + 1) * 128 + f];
    float w2 = W_glob[(c + 2) * 128 + f];
    float w3 = W_glob[(c + 3) * 128 + f];
#pragma unroll
    for (int i = 0; i < 8; ++i) {
      const floatx4 a4 = *(const floatx4*)&ag[h * 8 + i][c];
      acc[i] += a4[0] * w0 + a4[1] * w1 + a4[2] * w2 + a4[3] * w3;
    }
  }
#pragma unroll
  for (int i = 0; i < 8; ++i) {
    int m = mbase + h * 8 + i;
    if (m < M) out[m * 128 + f] = fmaxf(acc[i], 0.0f);
  }
}

// ---------------------------------------------------------------------------
extern "C" void kernel_launch(void* const* d_in, const int* in_sizes, int n_in,
                              void* d_out, int out_size, void* d_ws,
                              size_t ws_size, hipStream_t stream) {
  const float* x      = (const float*)d_in[0];
  const float* pos    = (const float*)d_in[1];
  const int*   idx    = (const int*)d_in[2];
  const float* W_pos  = (const float*)d_in[3];
  const float* b_pos  = (const float*)d_in[4];
  const float* W_att  = (const float*)d_in[5];
  const float* b_att  = (const float*)d_in[6];
  const float* W_glob = (const float*)d_in[7];
  const float* b_glob = (const float*)d_in[8];
  float* out = (float*)d_out;

  const int N = in_sizes[1] / 3;
  const int M = in_sizes[2];

  char* ws = (char*)d_ws;
  size_t o = 0;
  float4* pos4 = (float4*)(ws + o);               o += ((size_t)N * 16 + 255) & ~(size_t)255;
  unsigned short* xb = (unsigned short*)(ws + o); o += ((size_t)N * 128 + 255) & ~(size_t)255;
  unsigned short* Wt = (unsigned short*)(ws + o); o += (128 * 128 * 2 + 255) & ~(size_t)255;
  int* nbr = (int*)(ws + o);                      o += (((size_t)M * KNB * 4) + 255) & ~(size_t)255;
  int* ptcell = (int*)(ws + o);                   o += (((size_t)N * 4) + 255) & ~(size_t)255;
  int* count = (int*)(ws + o);                    o += ((size_t)GTOT * 4 + 255) & ~(size_t)255;
  int* cursor = (int*)(ws + o);                   o += ((size_t)GTOT * 4 + 255) & ~(size_t)255;
  int* cell_start = (int*)(ws + o);               o += ((size_t)(GTOT + 1) * 4 + 255) & ~(size_t)255;
  int* V = (int*)(ws + o);                        o += ((size_t)GTOT * 4 + 255) & ~(size_t)255;
  float4* spos4 = (float4*)(ws + o);              o += ((size_t)N * 16 + 255) & ~(size_t)255;
  int* sid = (int*)(ws + o);                      o += (((size_t)N * 4) + 255) & ~(size_t)255;
  float* aggr = (float*)(ws + o);                 o += ((size_t)M * 128 * 4 + 255) & ~(size_t)255;

  zero_kernel<<<GTOT / 1024, 256, 0, stream>>>(count);

  int prep_ids = N * 8 + N + 128 * 128;
  prep_kernel<<<(prep_ids + 255) / 256, 256, 0, stream>>>(
      x, pos, W_att, xb, pos4, Wt, ptcell, count, N);

  vscan_x<<<1024, 256, 0, stream>>>(count, V);
  vscan_y<<<1024, 256, 0, stream>>>(V);
  vscan_z<<<1024, 256, 0, stream>>>(V);
  derive_kernel<<<GTOT / 256, 256, 0, stream>>>(V, cell_start, cursor);

  scatter_kernel<<<(N + 255) / 256, 256, 0, stream>>>(pos4, ptcell, cursor,
                                                      spos4, sid, N);

  knn_grid<<<(M + 3) / 4, 256, 0, stream>>>(pos4, spos4, sid, cell_start, V,
                                            idx, nbr, M);

  mid_kernel<<<(M + 7) / 8, 256, 0, stream>>>(xb, pos4, idx, W_pos, b_pos, Wt,
                                              b_att, nbr, aggr, M);
  out_kernel<<<(M + 15) / 16, 256, 0, stream>>>(aggr, W_glob, b_glob, out, M);
}

// Round 15
// 202.961 us; speedup vs baseline: 1.3143x; 1.0039x over previous
//
#include <hip/hip_runtime.h>
#include <stdint.h>

#define KNB     16
#define GD      64                  // grid cells per axis
#define GTOT    (GD * GD * GD)      // 262144 cells
#define GORIG   (-6.5f)
#define GEDGE   0.203125f           // 13.0 / 64
#define GINV    (1.0f / GEDGE)
#define CAPW    640                 // per-query candidate capacity (10 x 64)
#define PROBE_T 48                  // min cube count for round-1 (>= KNB)

typedef short short8 __attribute__((ext_vector_type(8)));
typedef float floatx4 __attribute__((ext_vector_type(4)));

__device__ __forceinline__ unsigned short f2bf(float x) {
  union { float f; uint32_t u; } v; v.f = x;
  uint32_t u = v.u + 0x7FFFu + ((v.u >> 16) & 1u);   // RNE
  return (unsigned short)(u >> 16);
}
__device__ __forceinline__ float bf2f(unsigned short b) {
  return __uint_as_float(((uint32_t)b) << 16);
}
__device__ __forceinline__ int cellco(float v) {
  int c = (int)floorf((v - GORIG) * GINV);
  return c < 0 ? 0 : (c > GD - 1 ? GD - 1 : c);
}

// ---------------------------------------------------------------------------
// zero: count[GTOT] = 0  (must run before prep's atomics, every launch)
// ---------------------------------------------------------------------------
__global__ void zero_kernel(int* __restrict__ count) {
  int i = (blockIdx.x * 256 + threadIdx.x) * 4;
  *(int4*)(count + i) = make_int4(0, 0, 0, 0);
}

// ---------------------------------------------------------------------------
// prep: xb = bf16(x); pos4 = {x,y,z,pp}; ptcell[j] + count atomics; Wt.
// ---------------------------------------------------------------------------
__global__ void prep_kernel(const float* __restrict__ x,
                            const float* __restrict__ pos,
                            const float* __restrict__ W_att,
                            unsigned short* __restrict__ xb,
                            float4* __restrict__ pos4,
                            unsigned short* __restrict__ Wt,
                            int* __restrict__ ptcell,
                            int* __restrict__ count, int N) {
  int id = blockIdx.x * 256 + threadIdx.x;
  int nx8 = N * 8;
  if (id < nx8) {
    const float4* src = (const float4*)x + (size_t)id * 2;
    float4 a = src[0], b = src[1];
    short8 v;
    v[0] = (short)f2bf(a.x); v[1] = (short)f2bf(a.y);
    v[2] = (short)f2bf(a.z); v[3] = (short)f2bf(a.w);
    v[4] = (short)f2bf(b.x); v[5] = (short)f2bf(b.y);
    v[6] = (short)f2bf(b.z); v[7] = (short)f2bf(b.w);
    *(short8*)(xb + (size_t)id * 8) = v;
  } else if (id < nx8 + N) {
    int j = id - nx8;
    float px = pos[3 * j], py = pos[3 * j + 1], pz = pos[3 * j + 2];
    float pp = fmaf(px, px, fmaf(py, py, pz * pz));
    pos4[j] = make_float4(px, py, pz, pp);
    int cid = (cellco(pz) * GD + cellco(py)) * GD + cellco(px);
    ptcell[j] = cid;
    atomicAdd(&count[cid], 1);
  } else if (id < nx8 + N + 128 * 128) {
    int t = id - nx8 - N;
    int c = t >> 7, f = t & 127;
    Wt[f * 128 + c] = f2bf(W_att[t]);
  }
}

// ---------------------------------------------------------------------------
// summed-volume table V (3D inclusive prefix of per-cell counts), 3 passes.
// ---------------------------------------------------------------------------
__global__ __launch_bounds__(256) void vscan_x(const int* __restrict__ count,
                                               int* __restrict__ V) {
  int row = blockIdx.x * 4 + (threadIdx.x >> 6);
  int ln = threadIdx.x & 63;
  int i = row * GD + ln;
  int v = count[i];
#pragma unroll
  for (int off = 1; off < 64; off <<= 1) {
    int y = __shfl_up(v, off);
    if (ln >= off) v += y;
  }
  V[i] = v;
}

__global__ __launch_bounds__(256) void vscan_y(int* __restrict__ V) {
  int pair = blockIdx.x * 4 + (threadIdx.x >> 6);   // z*64 + x
  int z = pair >> 6, x = pair & 63;
  int ln = threadIdx.x & 63;                        // y
  int i = (z * GD + ln) * GD + x;
  int v = V[i];
#pragma unroll
  for (int off = 1; off < 64; off <<= 1) {
    int y = __shfl_up(v, off);
    if (ln >= off) v += y;
  }
  V[i] = v;
}

__global__ __launch_bounds__(256) void vscan_z(int* __restrict__ V) {
  int pair = blockIdx.x * 4 + (threadIdx.x >> 6);   // y*64 + x
  int ln = threadIdx.x & 63;                        // z
  int i = ln * GD * GD + pair;
  int v = V[i];
#pragma unroll
  for (int off = 1; off < 64; off <<= 1) {
    int y = __shfl_up(v, off);
    if (ln >= off) v += y;
  }
  V[i] = v;
}

// ---------------------------------------------------------------------------
// derive: cell_start (exclusive z-major prefix of per-cell counts) + cursor
// from the inclusive summed-volume table V.
// ---------------------------------------------------------------------------
__global__ __launch_bounds__(256) void derive_kernel(
    const int* __restrict__ V, int* __restrict__ cell_start,
    int* __restrict__ cursor) {
  int cid = blockIdx.x * 256 + threadIdx.x;
  int x = cid & 63, y = (cid >> 6) & 63, z = cid >> 12;
  int s = 0;
  if (z > 0) s += V[((z - 1) * GD + 63) * GD + 63];
  if (y > 0) {
    s += V[(z * GD + (y - 1)) * GD + 63];
    if (z > 0) s -= V[((z - 1) * GD + (y - 1)) * GD + 63];
  }
  if (x > 0) {
    s += V[(z * GD + y) * GD + (x - 1)];
    if (y > 0) s -= V[(z * GD + (y - 1)) * GD + (x - 1)];
    if (z > 0) s -= V[((z - 1) * GD + y) * GD + (x - 1)];
    if (z > 0 && y > 0) s += V[((z - 1) * GD + (y - 1)) * GD + (x - 1)];
  }
  cell_start[cid] = s;
  cursor[cid] = s;
  if (cid == 0) cell_start[GTOT] = V[GTOT - 1];   // = N
}

// ---------------------------------------------------------------------------
// scatter: points into cell-sorted order; original index j packed into the
// w component as bits (pp is recomputed bit-identically in the drain).
// ---------------------------------------------------------------------------
__global__ void scatter_kernel(const float4* __restrict__ pos4,
                               const int* __restrict__ ptcell,
                               int* __restrict__ cursor,
                               float4* __restrict__ spos4, int N) {
  int j = blockIdx.x * 256 + threadIdx.x;
  if (j >= N) return;
  int cid = ptcell[j];
  int slot = atomicAdd(&cursor[cid], 1);
  float4 p = pos4[j];
  spos4[slot] = make_float4(p.x, p.y, p.z, __int_as_float(j));
}

// ---------------------------------------------------------------------------
// top16_reg: exact top-16 of candw[0..tot) -> candw[0..16) (rank order);
// returns the 16th (largest) key. Whole wave active.
// ---------------------------------------------------------------------------
__device__ __forceinline__ unsigned long long top16_reg(
    unsigned long long* candw, int tot, int ln) {
  unsigned long long c[CAPW / 64];
#pragma unroll
  for (int chk = 0; chk < CAPW / 64; ++chk) {
    int slot = chk * 64 + ln;
    c[chk] = (slot < tot) ? candw[slot] : ~0ull;
  }
  unsigned long long mykey = ~0ull, last = 0;
#pragma unroll
  for (int r = 0; r < KNB; ++r) {
    unsigned long long mn = c[0];
#pragma unroll
    for (int chk = 1; chk < CAPW / 64; ++chk) mn = (c[chk] < mn) ? c[chk] : mn;
#pragma unroll
    for (int off = 1; off < 64; off <<= 1) {
      unsigned long long o = __shfl_xor(mn, off);
      mn = (o < mn) ? o : mn;
    }
    if (ln == r) mykey = mn;
    last = mn;
#pragma unroll
    for (int chk = 0; chk < CAPW / 64; ++chk)
      if (c[chk] == mn) c[chk] = ~0ull;
  }
  if (ln < KNB) candw[ln] = mykey;
  return last;
}

// ---------------------------------------------------------------------------
// drain_annulus: drain cells with Chebyshev radius in (slo, shi], clamped.
// Flat cooperative drain, register row tables + all-lane shfl binary search
// (R14-proven). NEW (R15): chunks processed in PAIRS — the two independent
// searches and the two point loads issue together so their latency chains
// overlap; ballots/stores follow. Validity folded into ok (all lanes stay
// active through every shfl). One 16B load per point (sid in spos4.w; pp
// recomputed with prep's exact fmaf chain -> bit-identical d2).
// Compacts to exact top-16 (taukey) before any pair could overflow CAPW.
// ---------------------------------------------------------------------------
__device__ __forceinline__ void drain_annulus(
    const float4* __restrict__ spos4, const int* __restrict__ cell_start,
    unsigned long long* candw, float4 qp, int cqx, int cqy, int cqz,
    int slo, int shi, int ln, int& tot, unsigned long long& taukey) {
  const int z0 = (cqz - shi < 0) ? 0 : cqz - shi;
  const int z1 = (cqz + shi > GD - 1) ? GD - 1 : cqz + shi;
  const int y0 = (cqy - shi < 0) ? 0 : cqy - shi;
  const int y1 = (cqy + shi > GD - 1) ? GD - 1 : cqy + shi;
  const int wy = y1 - y0 + 1;
  const int npair = (z1 - z0 + 1) * wy;
  for (int base = 0; base < npair; base += 64) {
    int i = base + ln;
    int stA = 0, lA = 0, stB = 0, lB = 0;
    if (i < npair) {
      int zz = z0 + i / wy;
      int yy = y0 + (i - (i / wy) * wy);
      int dz = zz - cqz, dy = yy - cqy;
      int az = dz < 0 ? -dz : dz, ay = dy < 0 ? -dy : dy;
      int ch = az > ay ? az : ay;
      int rowbase = (zz * GD + yy) * GD;
      if (ch > slo) {
        int x0 = cqx - shi; if (x0 < 0) x0 = 0;
        int x1 = cqx + shi; if (x1 > GD - 1) x1 = GD - 1;
        stA = cell_start[rowbase + x0];
        lA  = cell_start[rowbase + x1 + 1] - stA;
      } else {
        int xl0 = cqx - shi; if (xl0 < 0) xl0 = 0;
        int xl1 = cqx - slo - 1;
        if (xl1 >= xl0) {
          stA = cell_start[rowbase + xl0];
          lA  = cell_start[rowbase + xl1 + 1] - stA;
        }
        int xr0 = cqx + slo + 1;
        int xr1 = cqx + shi; if (xr1 > GD - 1) xr1 = GD - 1;
        if (xr1 >= xr0) {
          stB = cell_start[rowbase + xr0];
          lB  = cell_start[rowbase + xr1 + 1] - stB;
        }
      }
    }
    int len = lA + lB;
    int xinc = len;
#pragma unroll
    for (int off = 1; off < 64; off <<= 1) {
      int y = __shfl_up(xinc, off);
      if (ln >= off) xinc += y;
    }
    int T = __shfl(xinc, 63);
    if (T == 0) continue;
    int ps_ex = xinc - len;            // exclusive prefix (register, per-lane)

    for (int b2 = 0; b2 < T; b2 += 128) {
      if (tot + 128 > CAPW) {          // overflow-proof compaction (rare)
        taukey = top16_reg(candw, tot, ln);
        tot = KNB;
      }
      int flatA = b2 + ln;
      int flatB = b2 + 64 + ln;
      bool vA = flatA < T, vB = flatB < T;
      int fA = vA ? flatA : (T - 1);
      int fB = vB ? flatB : (T - 1);
      // dual shfl binary search (all lanes; independent chains)
      int loA = 0, loB = 0;
#pragma unroll
      for (int step = 32; step > 0; step >>= 1) {
        int mA = loA + step, mB = loB + step;
        int sA = __shfl(ps_ex, mA & 63);
        int sB = __shfl(ps_ex, mB & 63);
        if (mA <= 63 && sA <= fA) loA = mA;
        if (mB <= 63 && sB <= fB) loB = mB;
      }
      int psA = __shfl(ps_ex, loA), psB = __shfl(ps_ex, loB);
      int saA = __shfl(stA, loA),   saB = __shfl(stA, loB);
      int laA = __shfl(lA, loA),    laB = __shfl(lA, loB);
      int sbA = __shfl(stB, loA),   sbB = __shfl(stB, loB);
      int oA = fA - psA, oB = fB - psB;
      int pA = (oA < laA) ? (saA + oA) : (sbA + (oA - laA));
      int pB = (oB < laB) ? (saB + oB) : (sbB + (oB - laB));
      float4 pjA = spos4[pA];
      float4 pjB = spos4[pB];
      float ppA = fmaf(pjA.x, pjA.x, fmaf(pjA.y, pjA.y, pjA.z * pjA.z));
      float ppB = fmaf(pjB.x, pjB.x, fmaf(pjB.y, pjB.y, pjB.z * pjB.z));
      float dotA = fmaf(qp.x, pjA.x, fmaf(qp.y, pjA.y, qp.z * pjA.z));
      float dotB = fmaf(qp.x, pjB.x, fmaf(qp.y, pjB.y, qp.z * pjB.z));
      float d2A = fmaxf(qp.w + fmaf(-2.f, dotA, ppA), 0.f);
      float d2B = fmaxf(qp.w + fmaf(-2.f, dotB, ppB), 0.f);
      unsigned long long keyA =
          ((unsigned long long)__float_as_uint(d2A) << 32) |
          (uint32_t)__float_as_uint(pjA.w);
      unsigned long long keyB =
          ((unsigned long long)__float_as_uint(d2B) << 32) |
          (uint32_t)__float_as_uint(pjB.w);
      bool okA = vA && (keyA < taukey);
      bool okB = vB && (keyB < taukey);
      unsigned long long bmA = __ballot(okA);
      int posA = __popcll(bmA & ((1ull << ln) - 1ull));
      if (okA) candw[tot + posA] = keyA;
      tot += __popcll(bmA);
      unsigned long long bmB = __ballot(okB);
      int posB = __popcll(bmB & ((1ull << ln) - 1ull));
      if (okB) candw[tot + posB] = keyB;
      tot += __popcll(bmB);
    }
  }
}

// ---------------------------------------------------------------------------
// knn_grid (R15): ONE query per 64-thread block (fine scheduling
// granularity). Probe -> drain cube(s0) -> compact -> s1 -> annulus -> nbr.
// ---------------------------------------------------------------------------
__global__ __launch_bounds__(64) void knn_grid(
    const float4* __restrict__ pos4, const float4* __restrict__ spos4,
    const int* __restrict__ cell_start, const int* __restrict__ V,
    const int* __restrict__ idx, int* __restrict__ nbr, int M) {
  __shared__ unsigned long long cand[CAPW];
  const int ln = threadIdx.x;
  const int m = blockIdx.x;

  const float4 qp = pos4[idx[m]];
  const int cqx = cellco(qp.x), cqy = cellco(qp.y), cqz = cellco(qp.z);

  // --- lane-parallel minimal-cube probe via summed-volume table ---
  int s0;
  {
    int s = ln;
    int xh = cqx + s > GD - 1 ? GD - 1 : cqx + s;
    int yh = cqy + s > GD - 1 ? GD - 1 : cqy + s;
    int zh = cqz + s > GD - 1 ? GD - 1 : cqz + s;
    int xm = cqx - s - 1, ym = cqy - s - 1, zm = cqz - s - 1;
    int c = V[(zh * GD + yh) * GD + xh];
    if (zm >= 0) c -= V[(zm * GD + yh) * GD + xh];
    if (ym >= 0) c -= V[(zh * GD + ym) * GD + xh];
    if (xm >= 0) c -= V[(zh * GD + yh) * GD + xm];
    if (zm >= 0 && ym >= 0) c += V[(zm * GD + ym) * GD + xh];
    if (zm >= 0 && xm >= 0) c += V[(zm * GD + yh) * GD + xm];
    if (ym >= 0 && xm >= 0) c += V[(zh * GD + ym) * GD + xm];
    if (zm >= 0 && ym >= 0 && xm >= 0) c -= V[(zm * GD + ym) * GD + xm];
    unsigned long long bm = __ballot(c >= PROBE_T);
    s0 = __ffsll((unsigned long long)bm) - 1;   // bit 63 always set (c = N)
  }

  // --- round 1: drain cube(s0), compact to exact top-16 ---
  int tot = 0;
  unsigned long long taukey = ~0ull;
  drain_annulus(spos4, cell_start, cand, qp, cqx, cqy, cqz,
                -1, s0, ln, tot, taukey);
  taukey = top16_reg(cand, tot, ln);
  tot = KNB;
  float d16sq = __uint_as_float((uint32_t)(taukey >> 32));

  // --- s1: minimal radius whose guaranteed-explored ball covers d16 ---
  int s1 = s0;
  {
    float fx = qp.x - GORIG, fy = qp.y - GORIG, fz = qp.z - GORIG;
    while (s1 < GD - 1) {
      float r = 3.0e38f;
      if (cqx - s1 > 0)      r = fminf(r, fx - (float)(cqx - s1) * GEDGE);
      if (cqx + s1 < GD - 1) r = fminf(r, (float)(cqx + s1 + 1) * GEDGE - fx);
      if (cqy - s1 > 0)      r = fminf(r, fy - (float)(cqy - s1) * GEDGE);
      if (cqy + s1 < GD - 1) r = fminf(r, (float)(cqy + s1 + 1) * GEDGE - fy);
      if (cqz - s1 > 0)      r = fminf(r, fz - (float)(cqz - s1) * GEDGE);
      if (cqz + s1 < GD - 1) r = fminf(r, (float)(cqz + s1 + 1) * GEDGE - fz);
      float r2 = (r > 1.0e19f) ? 3.0e38f : r * r;
      if (r2 >= d16sq) break;
      ++s1;
    }
  }

  // --- round 2: drain annulus (s0, s1] with taukey filter ---
  if (s1 > s0) {
    drain_annulus(spos4, cell_start, cand, qp, cqx, cqy, cqz,
                  s0, s1, ln, tot, taukey);
    if (tot > KNB) (void)top16_reg(cand, tot, ln);
  }

  if (ln < KNB) nbr[m * KNB + ln] = (int)(uint32_t)cand[ln];
}

// ---------------------------------------------------------------------------
// mid: 8 queries / 256-thread block (unchanged from passing version).
// ---------------------------------------------------------------------------
__global__ __launch_bounds__(256) void mid_kernel(
    const unsigned short* __restrict__ xb, const float4* __restrict__ pos4,
    const int* __restrict__ idx, const float* __restrict__ W_pos,
    const float* __restrict__ b_pos, const unsigned short* __restrict__ Wt,
    const float* __restrict__ b_att, const int* __restrict__ nbr,
    float* __restrict__ aggr, int M) {
  __shared__ __align__(16) unsigned short fijb[8][16][136];
  __shared__ int nbr_s[128];
  __shared__ float4 qpos_s[8];

  const int tid = threadIdx.x;
  const int wid = tid >> 6, lane = tid & 63;
  const int col = lane & 15, quad = lane >> 4;
  const int b = blockIdx.x;

  if (tid < 128) {
    int mq = b * 8 + (tid >> 4); if (mq >= M) mq = M - 1;
    nbr_s[tid] = nbr[mq * 16 + (tid & 15)];
  }
  if (tid < 8) {
    int mq = b * 8 + tid; if (mq >= M) mq = M - 1;
    qpos_s[tid] = pos4[idx[mq]];
  }
  float wp[10];
#pragma unroll
  for (int t = 0; t < 10; ++t) wp[t] = W_pos[t * 64 + lane];
  float bp = b_pos[lane];
  __syncthreads();

  {
    int rr = tid >> 1, h = tid & 1;
    int jn = nbr_s[rr];
    const short8* src = (const short8*)(xb + ((size_t)jn << 6) + (h << 5));
    short8 v0 = src[0], v1 = src[1], v2 = src[2], v3 = src[3];
    short8* dst = (short8*)&fijb[rr >> 4][rr & 15][h * 32];
    dst[0] = v0; dst[1] = v1; dst[2] = v2; dst[3] = v3;
  }
#pragma unroll
  for (int qi = 0; qi < 2; ++qi) {
    int q = wid * 2 + qi;
    float4 qp = qpos_s[q];
#pragma unroll 4
    for (int k = 0; k < 16; ++k) {
      int jn = nbr_s[q * 16 + k];
      float4 pj = pos4[jn];
      float vx = qp.x - pj.x, vy = qp.y - pj.y, vz = qp.z - pj.z;
      float dd = sqrtf(fmaf(vx, vx, fmaf(vy, vy, vz * vz)));
      float r = bp;
      r = fmaf(qp.x, wp[0], r); r = fmaf(qp.y, wp[1], r); r = fmaf(qp.z, wp[2], r);
      r = fmaf(pj.x, wp[3], r); r = fmaf(pj.y, wp[4], r); r = fmaf(pj.z, wp[5], r);
      r = fmaf(vx, wp[6], r);  r = fmaf(vy, wp[7], r);  r = fmaf(vz, wp[8], r);
      r = fmaf(dd, wp[9], r);
      r = fmaxf(r, 0.f);
      fijb[q][k][64 + lane] = f2bf(r);
    }
  }
  __syncthreads();

#pragma unroll 1
  for (int qi = 0; qi < 2; ++qi) {
    int q = wid * 2 + qi;
    int mq = b * 8 + q;

    short8 af[4];
#pragma unroll
    for (int cs = 0; cs < 4; ++cs)
      af[cs] = *(const short8*)&fijb[q][col][cs * 32 + quad * 8];

    floatx4 acc[8];
#pragma unroll
    for (int ft = 0; ft < 8; ++ft) {
      float bav = b_att[ft * 16 + col];
      floatx4 a = {bav, bav, bav, bav};
#pragma unroll
      for (int cs = 0; cs < 4; ++cs) {
        short8 bfrag =
            *(const short8*)&Wt[(ft * 16 + col) * 128 + cs * 32 + quad * 8];
        a = __builtin_amdgcn_mfma_f32_16x16x32_bf16(af[cs], bfrag, a, 0, 0, 0);
      }
      acc[ft] = a;
    }

    float rowmax[4], rowinv[4];
#pragma unroll
    for (int r = 0; r < 4; ++r) {
      float mx = acc[0][r];
#pragma unroll
      for (int ft = 1; ft < 8; ++ft) mx = fmaxf(mx, acc[ft][r]);
      mx = fmaxf(mx, __shfl_xor(mx, 1));
      mx = fmaxf(mx, __shfl_xor(mx, 2));
      mx = fmaxf(mx, __shfl_xor(mx, 4));
      mx = fmaxf(mx, __shfl_xor(mx, 8));
      float sm = 0.f;
#pragma unroll
      for (int ft = 0; ft < 8; ++ft) sm += __expf(acc[ft][r] - mx);
      sm += __shfl_xor(sm, 1);
      sm += __shfl_xor(sm, 2);
      sm += __shfl_xor(sm, 4);
      sm += __shfl_xor(sm, 8);
      rowmax[r] = mx;
      rowinv[r] = 1.0f / sm;
    }

#pragma unroll
    for (int ft = 0; ft < 8; ++ft) {
      float ap = 0.f;
#pragma unroll
      for (int r = 0; r < 4; ++r) {
        float s = __expf(acc[ft][r] - rowmax[r]) * rowinv[r];
        float fv = bf2f(fijb[q][quad * 4 + r][ft * 16 + col]);
        ap = fmaf(s, fv, ap);
      }
      ap += __shfl_xor(ap, 16);
      ap += __shfl_xor(ap, 32);
      if (quad == 0 && mq < M)
        aggr[mq * 128 + ft * 16 + col] = ap * (1.0f / 16.0f);
    }
  }
}

// ---------------------------------------------------------------------------
// out = relu(aggr @ W_glob + b_glob)
// ---------------------------------------------------------------------------
__global__ __launch_bounds__(256) void out_kernel(
    const float* __restrict__ aggr, const float* __restrict__ W_glob,
    const float* __restrict__ b_glob, float* __restrict__ out, int M) {
  __shared__ float ag[16][128];
  const int tid = threadIdx.x;
  const int mbase = blockIdx.x * 16;
  for (int s = tid; s < 16 * 128; s += 256) {
    int r = s >> 7, cc = s & 127;
    int m = mbase + r;
    ((float*)ag)[s] = (m < M) ? aggr[m * 128 + cc] : 0.0f;
  }
  __syncthreads();
  const int f = tid & 127, h = tid >> 7;
  float acc[8];
  float bg = b_glob[f];
#pragma unroll
  for (int i = 0; i < 8; ++i) acc[i] = bg;
  for (int c = 0; c < 128; c += 4) {
    float w0 = W_glob[(c + 0) * 128 + f];
    float w1 = W_glob[(c + 1) * 128 + f];
    float w2 = W_glob[(c + 2) * 128 + f];
    float w3 = W_glob[(c + 3) * 128 + f];
#pragma unroll
    for (int i = 0; i < 8; ++i) {
      const floatx4 a4 = *(const floatx4*)&ag[h * 8 + i][c];
      acc[i] += a4[0] * w0 + a4[1] * w1 + a4[2] * w2 + a4[3] * w3;
    }
  }
#pragma unroll
  for (int i = 0; i < 8; ++i) {
    int m = mbase + h * 8 + i;
    if (m < M) out[m * 128 + f] = fmaxf(acc[i], 0.0f);
  }
}

// ---------------------------------------------------------------------------
extern "C" void kernel_launch(void* const* d_in, const int* in_sizes, int n_in,
                              void* d_out, int out_size, void* d_ws,
                              size_t ws_size, hipStream_t stream) {
  const float* x      = (const float*)d_in[0];
  const float* pos    = (const float*)d_in[1];
  const int*   idx    = (const int*)d_in[2];
  const float* W_pos  = (const float*)d_in[3];
  const float* b_pos  = (const float*)d_in[4];
  const float* W_att  = (const float*)d_in[5];
  const float* b_att  = (const float*)d_in[6];
  const float* W_glob = (const float*)d_in[7];
  const float* b_glob = (const float*)d_in[8];
  float* out = (float*)d_out;

  const int N = in_sizes[1] / 3;
  const int M = in_sizes[2];

  char* ws = (char*)d_ws;
  size_t o = 0;
  float4* pos4 = (float4*)(ws + o);               o += ((size_t)N * 16 + 255) & ~(size_t)255;
  unsigned short* xb = (unsigned short*)(ws + o); o += ((size_t)N * 128 + 255) & ~(size_t)255;
  unsigned short* Wt = (unsigned short*)(ws + o); o += (128 * 128 * 2 + 255) & ~(size_t)255;
  int* nbr = (int*)(ws + o);                      o += (((size_t)M * KNB * 4) + 255) & ~(size_t)255;
  int* ptcell = (int*)(ws + o);                   o += (((size_t)N * 4) + 255) & ~(size_t)255;
  int* count = (int*)(ws + o);                    o += ((size_t)GTOT * 4 + 255) & ~(size_t)255;
  int* cursor = (int*)(ws + o);                   o += ((size_t)GTOT * 4 + 255) & ~(size_t)255;
  int* cell_start = (int*)(ws + o);               o += ((size_t)(GTOT + 1) * 4 + 255) & ~(size_t)255;
  int* V = (int*)(ws + o);                        o += ((size_t)GTOT * 4 + 255) & ~(size_t)255;
  float4* spos4 = (float4*)(ws + o);              o += ((size_t)N * 16 + 255) & ~(size_t)255;
  float* aggr = (float*)(ws + o);                 o += ((size_t)M * 128 * 4 + 255) & ~(size_t)255;

  zero_kernel<<<GTOT / 1024, 256, 0, stream>>>(count);

  int prep_ids = N * 8 + N + 128 * 128;
  prep_kernel<<<(prep_ids + 255) / 256, 256, 0, stream>>>(
      x, pos, W_att, xb, pos4, Wt, ptcell, count, N);

  vscan_x<<<1024, 256, 0, stream>>>(count, V);
  vscan_y<<<1024, 256, 0, stream>>>(V);
  vscan_z<<<1024, 256, 0, stream>>>(V);
  derive_kernel<<<GTOT / 256, 256, 0, stream>>>(V, cell_start, cursor);

  scatter_kernel<<<(N + 255) / 256, 256, 0, stream>>>(pos4, ptcell, cursor,
                                                      spos4, N);

  knn_grid<<<M, 64, 0, stream>>>(pos4, spos4, cell_start, V, idx, nbr, M);

  mid_kernel<<<(M + 7) / 8, 256, 0, stream>>>(xb, pos4, idx, W_pos, b_pos, Wt,
                                              b_att, nbr, aggr, M);
  out_kernel<<<(M + 15) / 16, 256, 0, stream>>>(aggr, W_glob, b_glob, out, M);
}